// Round 5
// baseline (6752.436 us; speedup 1.0000x reference)
//
#include <hip/hip_runtime.h>
#include <cstdint>
#include <cstddef>

// ViT-B/16 + token pruning. Round 5: 256x256 8-wave phase-pipelined MFMA GEMM
// (ring-4 LDS slots, counted vmcnt, 1 barrier/K-tile, setprio, XOR swizzle).
// Split bf16 via virtual-K (A planes [h,h,l] x B planes [h,l,h], K'=3K).

#define NTOK 197
#define NB 64
#define NHEAD 12
#define SL 99

typedef __attribute__((ext_vector_type(8))) short short8;
typedef __attribute__((ext_vector_type(4))) float f32x4;
typedef __attribute__((ext_vector_type(4))) unsigned short us4;

#define DEV static __device__ __forceinline__

DEV unsigned short f2bf(float f) {
    union { float f; unsigned int u; } v; v.f = f;
    unsigned int r = (v.u + 0x7FFFu + ((v.u >> 16) & 1u)) >> 16;
    return (unsigned short)r;
}
DEV float bf2f(unsigned short h) {
    union { float f; unsigned int u; } v; v.u = ((unsigned int)h) << 16;
    return v.f;
}
DEV void gload16(const void* g, void* l) {
    __builtin_amdgcn_global_load_lds((const __attribute__((address_space(1))) unsigned int*)g,
                                     (__attribute__((address_space(3))) unsigned int*)l, 16, 0, 0);
}

// ---------------------------------------------------------------- weight conversion
template<int SP>
__global__ __launch_bounds__(256) void cvt_layer_k(const float* __restrict__ qw,
                                                   const float* __restrict__ pw,
                                                   const float* __restrict__ f1,
                                                   const float* __restrict__ f2,
                                                   unsigned short* __restrict__ dh,
                                                   unsigned short* __restrict__ dl)
{
    size_t t = (size_t)blockIdx.x * 256 + threadIdx.x;
    size_t e = t * 4;
    const float* src; size_t loc;
    if (e < 1769472)      { src = qw; loc = e; }
    else if (e < 2359296) { src = pw; loc = e - 1769472; }
    else if (e < 4718592) { src = f1; loc = e - 2359296; }
    else                  { src = f2; loc = e - 4718592; }
    float4 v = *(const float4*)(src + loc);
    us4 hi; hi.x = f2bf(v.x); hi.y = f2bf(v.y); hi.z = f2bf(v.z); hi.w = f2bf(v.w);
    *(us4*)(dh + e) = hi;
    if (SP) {
        us4 lo;
        lo.x = f2bf(v.x - bf2f(hi.x)); lo.y = f2bf(v.y - bf2f(hi.y));
        lo.z = f2bf(v.z - bf2f(hi.z)); lo.w = f2bf(v.w - bf2f(hi.w));
        *(us4*)(dl + e) = lo;
    }
}

template<int SP>
__global__ __launch_bounds__(256) void cvt_simple_k(const float* __restrict__ src,
                                                    unsigned short* __restrict__ dh,
                                                    unsigned short* __restrict__ dl, int n4)
{
    int t = blockIdx.x * 256 + threadIdx.x;
    if (t >= n4) return;
    size_t e = (size_t)t * 4;
    float4 v = *(const float4*)(src + e);
    us4 hi; hi.x = f2bf(v.x); hi.y = f2bf(v.y); hi.z = f2bf(v.z); hi.w = f2bf(v.w);
    *(us4*)(dh + e) = hi;
    if (SP) {
        us4 lo;
        lo.x = f2bf(v.x - bf2f(hi.x)); lo.y = f2bf(v.y - bf2f(hi.y));
        lo.z = f2bf(v.z - bf2f(hi.z)); lo.w = f2bf(v.w - bf2f(hi.w));
        *(us4*)(dl + e) = lo;
    }
}

// ---------------------------------------------------------------- patch extract
__global__ __launch_bounds__(256) void patch_extract2_k(const float* __restrict__ img,
                                                        unsigned short* __restrict__ ph,
                                                        unsigned short* __restrict__ pl)
{
    int pi = blockIdx.x, b = blockIdx.y;
    int gy = pi / 14, gx = pi % 14;
    size_t obase = ((size_t)b * 196 + pi) * 768;
    for (int f = threadIdx.x; f < 768; f += 256) {
        int c = f >> 8, py = (f >> 4) & 15, px = f & 15;
        float v = img[(((size_t)b * 3 + c) * 224 + gy * 16 + py) * 224 + gx * 16 + px];
        unsigned short hi = f2bf(v);
        ph[obase + f] = hi;
        pl[obase + f] = f2bf(v - bf2f(hi));
    }
}

__global__ __launch_bounds__(256) void assemble_k(const float* __restrict__ emb,
                                                  const float* __restrict__ cls,
                                                  const float* __restrict__ pos,
                                                  float* __restrict__ x)
{
    int s = blockIdx.x, b = blockIdx.y;
    size_t xo = ((size_t)b * NTOK + s) * 768;
    for (int d = threadIdx.x; d < 768; d += 256) {
        float v = (s == 0) ? cls[d] : emb[((size_t)b * 196 + (s - 1)) * 768 + d];
        x[xo + d] = v + pos[(size_t)s * 768 + d];
    }
}

// ---------------------------------------------------------------- layernorm fp32 -> bf16 (OS=2: +lo plane)
template<int OS>
__global__ __launch_bounds__(256) void ln2_k(const float* __restrict__ in,
                                             unsigned short* __restrict__ outh,
                                             unsigned short* __restrict__ outl,
                                             const float* __restrict__ g,
                                             const float* __restrict__ bt, size_t ldin)
{
    const float* xr = in + (size_t)blockIdx.x * ldin;
    size_t ob = (size_t)blockIdx.x * 768;
    int t = threadIdx.x;
    float v0 = xr[t], v1 = xr[t + 256], v2 = xr[t + 512];
    float s = v0 + v1 + v2;
#pragma unroll
    for (int o = 32; o; o >>= 1) s += __shfl_xor(s, o);
    __shared__ float r1[4], r2[4];
    int wv = t >> 6, ln = t & 63;
    if (ln == 0) r1[wv] = s;
    __syncthreads();
    float mean = (r1[0] + r1[1] + r1[2] + r1[3]) * (1.f / 768.f);
    float d0 = v0 - mean, d1 = v1 - mean, d2 = v2 - mean;
    float ss = d0 * d0 + d1 * d1 + d2 * d2;
#pragma unroll
    for (int o = 32; o; o >>= 1) ss += __shfl_xor(ss, o);
    if (ln == 0) r2[wv] = ss;
    __syncthreads();
    float inv = rsqrtf((r2[0] + r2[1] + r2[2] + r2[3]) * (1.f / 768.f) + 1e-6f);
    float y0 = d0 * inv * g[t] + bt[t];
    float y1 = d1 * inv * g[t + 256] + bt[t + 256];
    float y2 = d2 * inv * g[t + 512] + bt[t + 512];
    unsigned short h0 = f2bf(y0), h1 = f2bf(y1), h2 = f2bf(y2);
    outh[ob + t] = h0; outh[ob + t + 256] = h1; outh[ob + t + 512] = h2;
    if (OS == 2) {
        outl[ob + t] = f2bf(y0 - bf2f(h0));
        outl[ob + t + 256] = f2bf(y1 - bf2f(h1));
        outl[ob + t + 512] = f2bf(y2 - bf2f(h2));
    }
}

// ---------------------------------------------------------------- 256x256 8-wave phase-pipelined GEMM
// C = op(A@W^T + bias [+res]). A[M,K], W[N,K] bf16. VK=1: virtual K'=3K with
// A planes [h,h,l], B planes [h,l,h] (exact 3-product split accumulation).
// 8 waves (2Mx4N), wave tile 128x64, BK=32, ring of 4 LDS slots (128 KiB).
// Iteration kt: vmcnt(8 counted) -> s_barrier -> 4 phases {ds_read ahead,
// stage kt+3, setprio MFMA cluster}. EPI: 0 none, 1 GELU, 2 +res.
// OS: 0 fp32, 1 bf16, 2 bf16 split.
template<int VK, int EPI, int OS>
__global__ __launch_bounds__(512, 2) void gemm256_k(const unsigned short* __restrict__ Ah,
                                                    const unsigned short* __restrict__ Al,
                                                    const unsigned short* __restrict__ Wh,
                                                    const unsigned short* __restrict__ Wl,
                                                    const float* __restrict__ bias,
                                                    const float* __restrict__ res,
                                                    unsigned short* __restrict__ Chi,
                                                    unsigned short* __restrict__ Clo,
                                                    float* __restrict__ Cf,
                                                    int M, int N, int K, int nR, int nC)
{
    extern __shared__ unsigned short lds[];   // 4 slots x (A 8192 + B 8192) shorts = 128 KiB

    const int xcd = blockIdx.x & 7, u = blockIdx.x >> 3;
    const int ct = u % nC, rl = u / nC;
    const int rt = xcd + 8 * rl;
    if (rt >= nR) return;
    const int row0 = rt << 8, col0 = ct << 8;

    const int tid = threadIdx.x;
    const int w = tid >> 6, lane = tid & 63;
    const int wr = w >> 2, wc = w & 3;            // 2 x 4 wave grid
    const int fr = lane & 15, fq = lane >> 4;
    const int aoff = (fq ^ (fr & 3)) << 3;        // swizzled read chunk (shorts)

    const int kseg = K >> 5;
    const int nk = VK ? 3 * kseg : kseg;

    // staging geometry: wave w covers LDS rows (w*2+j)*16 + (lane>>2), j=0,1
    const int r0 = (w << 1) * 16 + (lane >> 2);
    const int r1 = r0 + 16;
    const int cs0 = (((lane & 3) ^ (r0 & 3)) << 3);   // pre-swizzled source chunk (shorts)
    const int cs1 = (((lane & 3) ^ (r1 & 3)) << 3);
    const int gA0 = (row0 + r0 < M) ? row0 + r0 : M - 1;
    const int gA1 = (row0 + r1 < M) ? row0 + r1 : M - 1;
    const int gB0 = (col0 + r0 < N) ? col0 + r0 : N - 1;
    const int gB1 = (col0 + r1 < N) ? col0 + r1 : N - 1;

    auto stageA = [&](int kt) {
        const unsigned short* As = (!VK || kt < 2 * kseg) ? Ah : Al;
        const int k0 = (VK ? (kt >= kseg ? (kt >= 2 * kseg ? kt - 2 * kseg : kt - kseg) : kt) : kt) << 5;
        unsigned short* dst = lds + (kt & 3) * 16384 + ((w << 1) << 9);
        gload16(As + (size_t)gA0 * K + k0 + cs0, dst);
        gload16(As + (size_t)gA1 * K + k0 + cs1, dst + 512);
    };
    auto stageB = [&](int kt) {
        const unsigned short* Bs = (VK && kt >= kseg && kt < 2 * kseg) ? Wl : Wh;
        const int k0 = (VK ? (kt >= kseg ? (kt >= 2 * kseg ? kt - 2 * kseg : kt - kseg) : kt) : kt) << 5;
        unsigned short* dst = lds + (kt & 3) * 16384 + 8192 + ((w << 1) << 9);
        gload16(Bs + (size_t)gB0 * K + k0 + cs0, dst);
        gload16(Bs + (size_t)gB1 * K + k0 + cs1, dst + 512);
    };

    f32x4 acc[8][4];
#pragma unroll
    for (int m = 0; m < 8; m++)
#pragma unroll
        for (int n = 0; n < 4; n++) acc[m][n] = (f32x4)0.f;

    // prologue: stage 3 tiles (12 loads in flight)
    stageA(0); stageB(0);
    if (nk > 1) { stageA(1); stageB(1); }
    if (nk > 2) { stageA(2); stageB(2); }

#define MF4(m, av) { \
    acc[m][0] = __builtin_amdgcn_mfma_f32_16x16x32_bf16(av, b0, acc[m][0], 0, 0, 0); \
    acc[m][1] = __builtin_amdgcn_mfma_f32_16x16x32_bf16(av, b1, acc[m][1], 0, 0, 0); \
    acc[m][2] = __builtin_amdgcn_mfma_f32_16x16x32_bf16(av, b2, acc[m][2], 0, 0, 0); \
    acc[m][3] = __builtin_amdgcn_mfma_f32_16x16x32_bf16(av, b3, acc[m][3], 0, 0, 0); }

    for (int kt = 0; kt < nk; ++kt) {
        if (kt + 2 < nk)      asm volatile("s_waitcnt vmcnt(8)" ::: "memory");
        else if (kt + 1 < nk) asm volatile("s_waitcnt vmcnt(4)" ::: "memory");
        else                  asm volatile("s_waitcnt vmcnt(0)" ::: "memory");
        __builtin_amdgcn_s_barrier();        // slot kt fully valid for all waves
        const unsigned short* sA = lds + (kt & 3) * 16384;
        const unsigned short* sB = sA + 8192;

        short8 b0 = *(const short8*)(sB + ((wc << 6) +  0 + fr) * 32 + aoff);
        short8 b1 = *(const short8*)(sB + ((wc << 6) + 16 + fr) * 32 + aoff);
        short8 b2 = *(const short8*)(sB + ((wc << 6) + 32 + fr) * 32 + aoff);
        short8 b3 = *(const short8*)(sB + ((wc << 6) + 48 + fr) * 32 + aoff);
        short8 a0 = *(const short8*)(sA + ((wr << 7) +   0 + fr) * 32 + aoff);
        short8 a1 = *(const short8*)(sA + ((wr << 7) +  16 + fr) * 32 + aoff);
        __builtin_amdgcn_sched_barrier(0);
        if (kt + 3 < nk) stageA(kt + 3);
        __builtin_amdgcn_sched_barrier(0);
        short8 a2 = *(const short8*)(sA + ((wr << 7) +  32 + fr) * 32 + aoff);
        short8 a3 = *(const short8*)(sA + ((wr << 7) +  48 + fr) * 32 + aoff);
        __builtin_amdgcn_sched_barrier(0);
        __builtin_amdgcn_s_setprio(1);
        MF4(0, a0); MF4(1, a1);
        __builtin_amdgcn_s_setprio(0);
        __builtin_amdgcn_sched_barrier(0);
        if (kt + 3 < nk) stageB(kt + 3);
        __builtin_amdgcn_sched_barrier(0);
        short8 a4 = *(const short8*)(sA + ((wr << 7) +  64 + fr) * 32 + aoff);
        short8 a5 = *(const short8*)(sA + ((wr << 7) +  80 + fr) * 32 + aoff);
        __builtin_amdgcn_sched_barrier(0);
        __builtin_amdgcn_s_setprio(1);
        MF4(2, a2); MF4(3, a3);
        __builtin_amdgcn_s_setprio(0);
        __builtin_amdgcn_sched_barrier(0);
        short8 a6 = *(const short8*)(sA + ((wr << 7) +  96 + fr) * 32 + aoff);
        short8 a7 = *(const short8*)(sA + ((wr << 7) + 112 + fr) * 32 + aoff);
        __builtin_amdgcn_sched_barrier(0);
        __builtin_amdgcn_s_setprio(1);
        MF4(4, a4); MF4(5, a5);
        __builtin_amdgcn_s_setprio(0);
        __builtin_amdgcn_sched_barrier(0);
        __builtin_amdgcn_s_setprio(1);
        MF4(6, a6); MF4(7, a7);
        __builtin_amdgcn_s_setprio(0);
        asm volatile("s_waitcnt lgkmcnt(0)" ::: "memory");  // reads retired before next barrier
        __builtin_amdgcn_sched_barrier(0);
    }
#undef MF4

#pragma unroll
    for (int m = 0; m < 8; m++) {
        const int rowb = row0 + (wr << 7) + (m << 4) + (fq << 2);
#pragma unroll
        for (int n = 0; n < 4; n++) {
            const int col = col0 + (wc << 6) + (n << 4) + fr;
            if (col >= N) continue;
#pragma unroll
            for (int r = 0; r < 4; r++) {
                const int row = rowb + r;
                if (row >= M) continue;
                float v = acc[m][n][r] + bias[col];
                size_t o = (size_t)row * N + col;
                if (EPI == 2) v += res[o];
                if (EPI == 1) v = 0.5f * v * (1.f + erff(v * 0.70710678118654752f));
                if (OS == 0) Cf[o] = v;
                else if (OS == 1) Chi[o] = f2bf(v);
                else { unsigned short hh = f2bf(v); Chi[o] = hh; Clo[o] = f2bf(v - bf2f(hh)); }
            }
        }
    }
}

// ---------------------------------------------------------------- 128x128 GEMM (R4) for small shapes
template<int SPLIT, int EPI, int OS, int MAP>
__global__ __launch_bounds__(256) void mgemm_k(const unsigned short* __restrict__ Ah,
                                               const unsigned short* __restrict__ Al,
                                               const unsigned short* __restrict__ Wh,
                                               const unsigned short* __restrict__ Wl,
                                               const float* __restrict__ bias,
                                               const float* __restrict__ res,
                                               unsigned short* __restrict__ Chi,
                                               unsigned short* __restrict__ Clo,
                                               float* __restrict__ Cf,
                                               int M, int N, int K, int nR, int nC, int nRmax)
{
    constexpr int NP = SPLIT ? 2 : 1;
    __shared__ unsigned short lds[2 * NP * 8192];

    int rt, ct;
    {
        int bid = blockIdx.x;
        if (MAP == 0) { rt = bid % nR; ct = bid / nR; }
        else {
            int x = bid & 7, u = bid >> 3, rl, c;
            if (MAP == 2) { c = u % nC; rl = u / nC; }
            else          { rl = u % nRmax; c = u / nRmax; }
            rt = x + 8 * rl; ct = c;
            if (rt >= nR) return;
        }
    }
    const int row0 = rt << 7, col0 = ct << 7;
    const int tid = threadIdx.x;
    const int w = tid >> 6, lane = tid & 63;
    const int wr = w >> 1, wc = w & 1;
    const int srow = lane >> 2;
    const int schunk = ((lane & 3) ^ ((srow >> 1) & 3)) << 3;
    const int fr = lane & 15, fq = lane >> 4;
    const int rchunk = (fq ^ ((fr >> 1) & 3)) << 3;

    f32x4 acc[4][4];
#pragma unroll
    for (int m = 0; m < 4; m++)
#pragma unroll
        for (int n = 0; n < 4; n++) acc[m][n] = (f32x4)0.f;

    const int nk = K >> 5;

    auto stage = [&](int t, int bsel) {
        const int k0 = t << 5;
        unsigned short* Ad = lds + bsel * NP * 8192;
        unsigned short* Bd = Ad + NP * 4096;
#pragma unroll
        for (int p = 0; p < NP; p++) {
            const unsigned short* Ap = p ? Al : Ah;
            const unsigned short* Wp = p ? Wl : Wh;
#pragma unroll
            for (int i = 0; i < 2; i++) {
                int r = i * 64 + w * 16 + srow;
                int ga = row0 + r; if (ga > M - 1) ga = M - 1;
                int gb = col0 + r; if (gb > N - 1) gb = N - 1;
                gload16(Ap + (size_t)ga * K + k0 + schunk, Ad + p * 4096 + i * 2048 + w * 512);
                gload16(Wp + (size_t)gb * K + k0 + schunk, Bd + p * 4096 + i * 2048 + w * 512);
            }
        }
    };

    stage(0, 0);
    stage(1, 1);
    for (int t = 0; t < nk; ++t) {
        const int bsel = t & 1;
        if (t + 1 < nk) {
            if constexpr (NP == 2) asm volatile("s_waitcnt vmcnt(8)" ::: "memory");
            else                   asm volatile("s_waitcnt vmcnt(4)" ::: "memory");
        } else {
            asm volatile("s_waitcnt vmcnt(0)" ::: "memory");
        }
        __builtin_amdgcn_s_barrier();
        __builtin_amdgcn_sched_barrier(0);
        const unsigned short* Ab = lds + bsel * NP * 8192;
        const unsigned short* Bb = Ab + NP * 4096;
        short8 a[NP][4], bb[NP][4];
#pragma unroll
        for (int p = 0; p < NP; p++)
#pragma unroll
            for (int m = 0; m < 4; m++)
                a[p][m] = *(const short8*)(Ab + p * 4096 + (wr * 64 + m * 16 + fr) * 32 + rchunk);
#pragma unroll
        for (int p = 0; p < NP; p++)
#pragma unroll
            for (int n = 0; n < 4; n++)
                bb[p][n] = *(const short8*)(Bb + p * 4096 + (wc * 64 + n * 16 + fr) * 32 + rchunk);
        __builtin_amdgcn_sched_barrier(0);
        asm volatile("s_waitcnt lgkmcnt(0)" ::: "memory");
        __builtin_amdgcn_sched_barrier(0);
        __builtin_amdgcn_s_barrier();
        if (t + 2 < nk) stage(t + 2, bsel);
#pragma unroll
        for (int m = 0; m < 4; m++)
#pragma unroll
            for (int n = 0; n < 4; n++) {
                acc[m][n] = __builtin_amdgcn_mfma_f32_16x16x32_bf16(a[0][m], bb[0][n], acc[m][n], 0, 0, 0);
                if (SPLIT) {
                    acc[m][n] = __builtin_amdgcn_mfma_f32_16x16x32_bf16(a[0][m], bb[1][n], acc[m][n], 0, 0, 0);
                    acc[m][n] = __builtin_amdgcn_mfma_f32_16x16x32_bf16(a[1][m], bb[0][n], acc[m][n], 0, 0, 0);
                }
            }
    }

#pragma unroll
    for (int m = 0; m < 4; m++) {
#pragma unroll
        for (int n = 0; n < 4; n++) {
            int col = col0 + wc * 64 + n * 16 + fr;
#pragma unroll
            for (int r = 0; r < 4; r++) {
                int row = row0 + wr * 64 + m * 16 + fq * 4 + r;
                if (row < M && col < N) {
                    float v = acc[m][n][r] + bias[col];
                    size_t o = (size_t)row * N + col;
                    if (EPI == 2) v += res[o];
                    if (EPI == 1) v = 0.5f * v * (1.f + erff(v * 0.70710678118654752f));
                    if (OS == 0) Cf[o] = v;
                    else if (OS == 1) Chi[o] = f2bf(v);
                    else { unsigned short hh = f2bf(v); Chi[o] = hh; Clo[o] = f2bf(v - bf2f(hh)); }
                }
            }
        }
    }
}

// ---------------------------------------------------------------- fused MFMA attention
template<int SPLIT, int S, int KT, int PVKT, int PSTR>
__global__ __launch_bounds__(256) void attn2_k(const unsigned short* __restrict__ qh,
                                               const unsigned short* __restrict__ ql,
                                               unsigned short* __restrict__ oh,
                                               unsigned short* __restrict__ ol,
                                               const int* __restrict__ cntp)
{
    constexpr int NP = SPLIT ? 2 : 1;
    constexpr int PVK = PVKT * 32;
    constexpr int QT = (S + 15) / 16;
    extern __shared__ unsigned short sh[];
    unsigned short* VT = sh;
    unsigned short* PL = sh + NP * 64 * PSTR;

    const int h = blockIdx.x, b = blockIdx.y;
    const int tid = threadIdx.x, w = tid >> 6, lane = tid & 63;
    const int nk = cntp ? cntp[b] : S;
    const size_t qbase = (size_t)b * S * 2304 + (size_t)h * 64;
    const int fr = lane & 15, fq = lane >> 4;

    for (int j0 = 0; j0 < S; j0 += 32) {
        int j = j0 + (tid >> 3);
        int d8 = (tid & 7) * 8;
        if (j < S) {
            size_t src = qbase + (size_t)j * 2304 + 1536 + d8;
#pragma unroll
            for (int p = 0; p < NP; p++) {
                const unsigned short* qp = p ? ql : qh;
                short8 v = *(const short8*)(qp + src);
#pragma unroll
                for (int e = 0; e < 8; e++)
                    VT[p * 64 * PSTR + (d8 + e) * PSTR + j] = ((unsigned short*)&v)[e];
            }
        }
    }
    for (int idx = tid; idx < 64 * (PVK - S); idx += 256) {
        int d = idx / (PVK - S), j = S + idx % (PVK - S);
#pragma unroll
        for (int p = 0; p < NP; p++) VT[p * 64 * PSTR + d * PSTR + j] = 0;
    }
    {
        unsigned short* Pw = PL + w * NP * 16 * PSTR;
        for (int idx = lane; idx < 16 * (PVK - 16 * KT); idx += 64) {
            int rr = idx / (PVK - 16 * KT), cc = 16 * KT + idx % (PVK - 16 * KT);
#pragma unroll
            for (int p = 0; p < NP; p++) Pw[p * 16 * PSTR + rr * PSTR + cc] = 0;
        }
    }
    __syncthreads();

    for (int qt = w; qt < QT; qt += 4) {
        int qr = qt * 16 + fr; int qrc = qr < S ? qr : S - 1;
        const size_t qrow = qbase + (size_t)qrc * 2304;
        short8 qf0[2], qf1[2];
#pragma unroll
        for (int ks = 0; ks < 2; ks++) {
            qf0[ks] = *(const short8*)(qh + qrow + ks * 32 + fq * 8);
            if (SPLIT) qf1[ks] = *(const short8*)(ql + qrow + ks * 32 + fq * 8);
        }
        f32x4 sc[KT];
#pragma unroll
        for (int kt = 0; kt < KT; kt++) {
            int ky = kt * 16 + fr; int kyc = ky < S ? ky : S - 1;
            const size_t krow = qbase + (size_t)kyc * 2304 + 768;
            f32x4 acc = (f32x4)0.f;
#pragma unroll
            for (int ks = 0; ks < 2; ks++) {
                short8 kh = *(const short8*)(qh + krow + ks * 32 + fq * 8);
                acc = __builtin_amdgcn_mfma_f32_16x16x32_bf16(qf0[ks], kh, acc, 0, 0, 0);
                if (SPLIT) {
                    short8 kl = *(const short8*)(ql + krow + ks * 32 + fq * 8);
                    acc = __builtin_amdgcn_mfma_f32_16x16x32_bf16(qf0[ks], kl, acc, 0, 0, 0);
                    acc = __builtin_amdgcn_mfma_f32_16x16x32_bf16(qf1[ks], kh, acc, 0, 0, 0);
                }
            }
            sc[kt] = acc;
        }
        float mx[4] = {-3e38f, -3e38f, -3e38f, -3e38f};
#pragma unroll
        for (int kt = 0; kt < KT; kt++) {
            bool valid = (kt * 16 + fr) < nk;
#pragma unroll
            for (int r = 0; r < 4; r++) {
                float s = sc[kt][r] * 0.125f;
                sc[kt][r] = s;
                if (valid) mx[r] = fmaxf(mx[r], s);
            }
        }
#pragma unroll
        for (int off = 1; off < 16; off <<= 1)
#pragma unroll
            for (int r = 0; r < 4; r++) mx[r] = fmaxf(mx[r], __shfl_xor(mx[r], off));
        float sum[4] = {0.f, 0.f, 0.f, 0.f};
#pragma unroll
        for (int kt = 0; kt < KT; kt++) {
            bool valid = (kt * 16 + fr) < nk;
#pragma unroll
            for (int r = 0; r < 4; r++) {
                float p = 0.f;
                if (valid) p = SPLIT ? expf(sc[kt][r] - mx[r]) : __expf(sc[kt][r] - mx[r]);
                sc[kt][r] = p;
                sum[r] += p;
            }
        }
#pragma unroll
        for (int off = 1; off < 16; off <<= 1)
#pragma unroll
            for (int r = 0; r < 4; r++) sum[r] += __shfl_xor(sum[r], off);
        float inv[4];
#pragma unroll
        for (int r = 0; r < 4; r++) inv[r] = 1.f / sum[r];
        unsigned short* Pw = PL + w * NP * 16 * PSTR;
#pragma unroll
        for (int kt = 0; kt < KT; kt++) {
#pragma unroll
            for (int r = 0; r < 4; r++) {
                float p = sc[kt][r] * inv[r];
                unsigned short hh = f2bf(p);
                Pw[(fq * 4 + r) * PSTR + kt * 16 + fr] = hh;
                if (SPLIT) Pw[16 * PSTR + (fq * 4 + r) * PSTR + kt * 16 + fr] = f2bf(p - bf2f(hh));
            }
        }
        f32x4 o[4];
#pragma unroll
        for (int n = 0; n < 4; n++) o[n] = (f32x4)0.f;
#pragma unroll
        for (int ks = 0; ks < PVKT; ks++) {
            short8 pa = *(const short8*)(Pw + fr * PSTR + ks * 32 + fq * 8);
            short8 pl2;
            if (SPLIT) pl2 = *(const short8*)(Pw + 16 * PSTR + fr * PSTR + ks * 32 + fq * 8);
#pragma unroll
            for (int n = 0; n < 4; n++) {
                short8 vb = *(const short8*)(VT + (n * 16 + fr) * PSTR + ks * 32 + fq * 8);
                o[n] = __builtin_amdgcn_mfma_f32_16x16x32_bf16(pa, vb, o[n], 0, 0, 0);
                if (SPLIT) {
                    short8 vl = *(const short8*)(VT + 64 * PSTR + (n * 16 + fr) * PSTR + ks * 32 + fq * 8);
                    o[n] = __builtin_amdgcn_mfma_f32_16x16x32_bf16(pa, vl, o[n], 0, 0, 0);
                    o[n] = __builtin_amdgcn_mfma_f32_16x16x32_bf16(pl2, vb, o[n], 0, 0, 0);
                }
            }
        }
#pragma unroll
        for (int n = 0; n < 4; n++) {
#pragma unroll
            for (int r = 0; r < 4; r++) {
                int row = qt * 16 + fq * 4 + r;
                if (row < S) {
                    size_t oidx = ((size_t)b * S + row) * 768 + (size_t)h * 64 + n * 16 + fr;
                    float vv = o[n][r];
                    unsigned short hh = f2bf(vv);
                    oh[oidx] = hh;
                    if (SPLIT) ol[oidx] = f2bf(vv - bf2f(hh));
                }
            }
        }
    }
}

// ---------------------------------------------------------------- prune machinery
__global__ __launch_bounds__(256) void normsq_k(const float* __restrict__ x, float* __restrict__ norms)
{
    const float* xr = x + (size_t)blockIdx.x * 768;
    int t = threadIdx.x;
    float v0 = xr[t], v1 = xr[t + 256], v2 = xr[t + 512];
    float ss = v0 * v0 + v1 * v1 + v2 * v2;
#pragma unroll
    for (int o = 32; o; o >>= 1) ss += __shfl_xor(ss, o);
    __shared__ float r1[4];
    if ((t & 63) == 0) r1[t >> 6] = ss;
    __syncthreads();
    if (t == 0) norms[blockIdx.x] = r1[0] + r1[1] + r1[2] + r1[3];
}

__global__ __launch_bounds__(256) void topk_k(const float* __restrict__ norms,
                                              int* __restrict__ idxmap, int* __restrict__ cnt)
{
    int b = blockIdx.x, t = threadIdx.x;
    __shared__ float n[NTOK];
    __shared__ unsigned char kp[NTOK];
    if (t < NTOK) n[t] = norms[b * NTOK + t];
    __syncthreads();
    if (t < NTOK) {
        float me = n[t];
        int rank = 0;
        for (int j = 0; j < NTOK; j++) rank += (n[j] > me) || (n[j] == me && j < t);
        kp[t] = (rank < 98) || (t == 0);
    }
    __syncthreads();
    if (t == 0) {
        int c = 0;
        for (int s = 0; s < NTOK; s++) if (kp[s]) idxmap[b * SL + c++] = s;
        cnt[b] = c;
        for (int j = c; j < SL; j++) idxmap[b * SL + j] = 0;
    }
}

__global__ __launch_bounds__(256) void gather_k(const float* __restrict__ x, const int* __restrict__ idxmap,
                                                const int* __restrict__ cnt, float* __restrict__ xl)
{
    int j = blockIdx.x, b = blockIdx.y;
    size_t dst = ((size_t)b * SL + j) * 768;
    if (j < cnt[b]) {
        int s = idxmap[b * SL + j];
        size_t src = ((size_t)b * NTOK + s) * 768;
        for (int d = threadIdx.x; d < 768; d += 256) xl[dst + d] = x[src + d];
    } else {
        for (int d = threadIdx.x; d < 768; d += 256) xl[dst + d] = 0.f;
    }
}

// ---------------------------------------------------------------- launch
extern "C" void kernel_launch(void* const* d_in, const int* in_sizes, int n_in,
                              void* d_out, int out_size, void* d_ws, size_t ws_size,
                              hipStream_t stream)
{
    const float* images  = (const float*)d_in[0];
    const float* patch_w = (const float*)d_in[1];
    const float* patch_b = (const float*)d_in[2];
    const float* cls_tok = (const float*)d_in[3];
    const float* pos_emb = (const float*)d_in[4];
    const float* ln1_g   = (const float*)d_in[5];
    const float* ln1_b   = (const float*)d_in[6];
    const float* qkv_w   = (const float*)d_in[7];
    const float* qkv_b   = (const float*)d_in[8];
    const float* proj_w  = (const float*)d_in[9];
    const float* proj_b  = (const float*)d_in[10];
    const float* ln2_g   = (const float*)d_in[11];
    const float* ln2_b   = (const float*)d_in[12];
    const float* fc1_w   = (const float*)d_in[13];
    const float* fc1_b   = (const float*)d_in[14];
    const float* fc2_w   = (const float*)d_in[15];
    const float* fc2_b   = (const float*)d_in[16];
    const float* norm_g  = (const float*)d_in[17];
    const float* norm_b  = (const float*)d_in[18];
    const float* head_w  = (const float*)d_in[19];
    const float* head_b  = (const float*)d_in[20];
    float* outp = (float*)d_out;

    char* W = (char*)d_ws;
    float* x = (float*)W;
    unsigned short* hbh = (unsigned short*)(W + 38731776);
    unsigned short* hbl = hbh + 9682944;
    char* R = W + 77463552;
    unsigned short* wbh = (unsigned short*)(W + 232390656);
    unsigned short* wbl = wbh + 7077888;
    unsigned short* pwh = (unsigned short*)(W + 260702208);
    unsigned short* pwl = pwh + 589824;
    unsigned short* hwb = (unsigned short*)(W + 263061504);
    float* norms = (float*)(W + 264634368);
    unsigned short* clsb = (unsigned short*)(W + 264684800);
    int* idxmap = (int*)(W + 264881408);
    int* cnt    = (int*)(W + 264906752);

    unsigned short* ph  = (unsigned short*)R;
    unsigned short* plo = ph + 9633792;
    float* emb = (float*)(R + 38535168);
    unsigned short* qkh = (unsigned short*)R;
    unsigned short* qkl = qkh + 29048832;
    unsigned short* ffh = (unsigned short*)R;
    unsigned short* ffl = ffh + 38731776;
    float* xl = (float*)(R + 41943040);

    const int LDS_EARLY = (2 * 64 * 232 + 4 * 2 * 16 * 232) * 2;   // 118,784
    const int LDS_LATE  = (1 * 64 * 136 + 4 * 1 * 16 * 136) * 2;   // 34,816
    const int LDS_G256  = 131072;
    (void)hipFuncSetAttribute(reinterpret_cast<const void*>(&attn2_k<1, 197, 13, 7, 232>),
                              hipFuncAttributeMaxDynamicSharedMemorySize, LDS_EARLY);
    (void)hipFuncSetAttribute(reinterpret_cast<const void*>(&attn2_k<0, 99, 7, 4, 136>),
                              hipFuncAttributeMaxDynamicSharedMemorySize, LDS_LATE);
    (void)hipFuncSetAttribute(reinterpret_cast<const void*>(&gemm256_k<1, 0, 0>),
                              hipFuncAttributeMaxDynamicSharedMemorySize, LDS_G256);
    (void)hipFuncSetAttribute(reinterpret_cast<const void*>(&gemm256_k<1, 0, 2>),
                              hipFuncAttributeMaxDynamicSharedMemorySize, LDS_G256);
    (void)hipFuncSetAttribute(reinterpret_cast<const void*>(&gemm256_k<1, 2, 0>),
                              hipFuncAttributeMaxDynamicSharedMemorySize, LDS_G256);
    (void)hipFuncSetAttribute(reinterpret_cast<const void*>(&gemm256_k<1, 1, 2>),
                              hipFuncAttributeMaxDynamicSharedMemorySize, LDS_G256);
    (void)hipFuncSetAttribute(reinterpret_cast<const void*>(&gemm256_k<0, 0, 1>),
                              hipFuncAttributeMaxDynamicSharedMemorySize, LDS_G256);
    (void)hipFuncSetAttribute(reinterpret_cast<const void*>(&gemm256_k<0, 1, 1>),
                              hipFuncAttributeMaxDynamicSharedMemorySize, LDS_G256);

    // 256-tile grids: grid = 8 * ceil(nR/8) * nC
    const int nR1 = 50, nR1c = 7;      // M = 12608
    const int nRp = 49, nRpc = 7;      // M = 12544
    const int nR2 = 25, nR2c = 4;      // M = 6336
    // 128-tile grids for late proj/fc2
    const int nRl = 50, nRlm = 7;      // M = 6336 in 128-rows

    // ---- patch embed (split via virtual-K) ----
    cvt_simple_k<1><<<576, 256, 0, stream>>>(patch_w, pwh, pwl, 147456);
    patch_extract2_k<<<dim3(196, NB), 256, 0, stream>>>(images, ph, plo);
    gemm256_k<1, 0, 0><<<8 * nRpc * 3, 512, LDS_G256, stream>>>(ph, plo, pwh, pwl, patch_b, nullptr,
        nullptr, nullptr, emb, 12544, 768, 768, nRp, 3);
    assemble_k<<<dim3(NTOK, NB), 256, 0, stream>>>(emb, cls_tok, pos_emb, x);

    const int M1 = NB * NTOK;   // 12608
    for (int i = 0; i < 4; i++) {
        cvt_layer_k<1><<<6912, 256, 0, stream>>>(qkv_w + (size_t)i * 1769472, proj_w + (size_t)i * 589824,
                                                 fc1_w + (size_t)i * 2359296, fc2_w + (size_t)i * 2359296,
                                                 wbh, wbl);
        ln2_k<2><<<M1, 256, 0, stream>>>(x, hbh, hbl, ln1_g + (size_t)i * 768, ln1_b + (size_t)i * 768, 768);
        gemm256_k<1, 0, 2><<<8 * nR1c * 9, 512, LDS_G256, stream>>>(hbh, hbl, wbh, wbl,
            qkv_b + (size_t)i * 2304, nullptr, qkh, qkl, nullptr, M1, 2304, 768, nR1, 9);
        attn2_k<1, 197, 13, 7, 232><<<dim3(NHEAD, NB), 256, LDS_EARLY, stream>>>(qkh, qkl, hbh, hbl, nullptr);
        gemm256_k<1, 2, 0><<<8 * nR1c * 3, 512, LDS_G256, stream>>>(hbh, hbl, wbh + 1769472, wbl + 1769472,
            proj_b + (size_t)i * 768, x, nullptr, nullptr, x, M1, 768, 768, nR1, 3);
        ln2_k<2><<<M1, 256, 0, stream>>>(x, hbh, hbl, ln2_g + (size_t)i * 768, ln2_b + (size_t)i * 768, 768);
        gemm256_k<1, 1, 2><<<8 * nR1c * 12, 512, LDS_G256, stream>>>(hbh, hbl, wbh + 2359296, wbl + 2359296,
            fc1_b + (size_t)i * 3072, nullptr, ffh, ffl, nullptr, M1, 3072, 768, nR1, 12);
        gemm256_k<1, 2, 0><<<8 * nR1c * 3, 512, LDS_G256, stream>>>(ffh, ffl, wbh + 4718592, wbl + 4718592,
            fc2_b + (size_t)i * 768, x, nullptr, nullptr, x, M1, 768, 3072, nR1, 3);
    }

    // ---- prune + compact ----
    normsq_k<<<M1, 256, 0, stream>>>(x, norms);
    topk_k<<<NB, 256, 0, stream>>>(norms, idxmap, cnt);
    gather_k<<<dim3(SL, NB), 256, 0, stream>>>(x, idxmap, cnt, xl);

    const int M2 = NB * SL;     // 6336
    for (int i = 4; i < 12; i++) {
        cvt_layer_k<0><<<6912, 256, 0, stream>>>(qkv_w + (size_t)i * 1769472, proj_w + (size_t)i * 589824,
                                                 fc1_w + (size_t)i * 2359296, fc2_w + (size_t)i * 2359296,
                                                 wbh, nullptr);
        ln2_k<1><<<M2, 256, 0, stream>>>(xl, hbh, nullptr, ln1_g + (size_t)i * 768, ln1_b + (size_t)i * 768, 768);
        gemm256_k<0, 0, 1><<<8 * nR2c * 9, 512, LDS_G256, stream>>>(hbh, nullptr, wbh, nullptr,
            qkv_b + (size_t)i * 2304, nullptr, qkh, nullptr, nullptr, M2, 2304, 768, nR2, 9);
        attn2_k<0, 99, 7, 4, 136><<<dim3(NHEAD, NB), 256, LDS_LATE, stream>>>(qkh, nullptr, hbl, nullptr, cnt);
        mgemm_k<0, 2, 0, 2><<<8 * nRlm * 6, 256, 0, stream>>>(hbl, nullptr, wbh + 1769472, nullptr,
            proj_b + (size_t)i * 768, xl, nullptr, nullptr, xl, M2, 768, 768, nRl, 6, nRlm);
        ln2_k<1><<<M2, 256, 0, stream>>>(xl, hbh, nullptr, ln2_g + (size_t)i * 768, ln2_b + (size_t)i * 768, 768);
        gemm256_k<0, 1, 1><<<8 * nR2c * 12, 512, LDS_G256, stream>>>(hbh, nullptr, wbh + 2359296, nullptr,
            fc1_b + (size_t)i * 3072, nullptr, ffh, nullptr, nullptr, M2, 3072, 768, nR2, 12);
        mgemm_k<0, 2, 0, 2><<<8 * nRlm * 6, 256, 0, stream>>>(ffh, nullptr, wbh + 4718592, nullptr,
            fc2_b + (size_t)i * 768, xl, nullptr, nullptr, xl, M2, 768, 3072, nRl, 6, nRlm);
    }

    // ---- final LN(CLS) + head ----
    ln2_k<1><<<NB, 256, 0, stream>>>(xl, clsb, nullptr, norm_g, norm_b, (size_t)SL * 768);
    cvt_simple_k<0><<<750, 256, 0, stream>>>(head_w, hwb, nullptr, 192000);
    mgemm_k<0, 0, 0, 0><<<8, 256, 0, stream>>>(clsb, nullptr, hwb, nullptr,
        head_b, nullptr, nullptr, nullptr, outp, 64, 1000, 768, 1, 8, 1);
}

// Round 6
// 6004.309 us; speedup vs baseline: 1.1246x; 1.1246x over previous
//
#include <hip/hip_runtime.h>
#include <cstdint>
#include <cstddef>

// ViT-B/16 + token pruning. Round 6: gemm256 swizzle fixed to sigma(r)=(r>>1)&3
// (2-way-free instead of 4-way conflict); gemm256 used only where grid >= 256
// blocks (early qkv, early fc1); all other GEMMs use the R4 128^2 kernel.

#define NTOK 197
#define NB 64
#define NHEAD 12
#define SL 99

typedef __attribute__((ext_vector_type(8))) short short8;
typedef __attribute__((ext_vector_type(4))) float f32x4;
typedef __attribute__((ext_vector_type(4))) unsigned short us4;

#define DEV static __device__ __forceinline__

DEV unsigned short f2bf(float f) {
    union { float f; unsigned int u; } v; v.f = f;
    unsigned int r = (v.u + 0x7FFFu + ((v.u >> 16) & 1u)) >> 16;
    return (unsigned short)r;
}
DEV float bf2f(unsigned short h) {
    union { float f; unsigned int u; } v; v.u = ((unsigned int)h) << 16;
    return v.f;
}
DEV void gload16(const void* g, void* l) {
    __builtin_amdgcn_global_load_lds((const __attribute__((address_space(1))) unsigned int*)g,
                                     (__attribute__((address_space(3))) unsigned int*)l, 16, 0, 0);
}

// ---------------------------------------------------------------- weight conversion
template<int SP>
__global__ __launch_bounds__(256) void cvt_layer_k(const float* __restrict__ qw,
                                                   const float* __restrict__ pw,
                                                   const float* __restrict__ f1,
                                                   const float* __restrict__ f2,
                                                   unsigned short* __restrict__ dh,
                                                   unsigned short* __restrict__ dl)
{
    size_t t = (size_t)blockIdx.x * 256 + threadIdx.x;
    size_t e = t * 4;
    const float* src; size_t loc;
    if (e < 1769472)      { src = qw; loc = e; }
    else if (e < 2359296) { src = pw; loc = e - 1769472; }
    else if (e < 4718592) { src = f1; loc = e - 2359296; }
    else                  { src = f2; loc = e - 4718592; }
    float4 v = *(const float4*)(src + loc);
    us4 hi; hi.x = f2bf(v.x); hi.y = f2bf(v.y); hi.z = f2bf(v.z); hi.w = f2bf(v.w);
    *(us4*)(dh + e) = hi;
    if (SP) {
        us4 lo;
        lo.x = f2bf(v.x - bf2f(hi.x)); lo.y = f2bf(v.y - bf2f(hi.y));
        lo.z = f2bf(v.z - bf2f(hi.z)); lo.w = f2bf(v.w - bf2f(hi.w));
        *(us4*)(dl + e) = lo;
    }
}

template<int SP>
__global__ __launch_bounds__(256) void cvt_simple_k(const float* __restrict__ src,
                                                    unsigned short* __restrict__ dh,
                                                    unsigned short* __restrict__ dl, int n4)
{
    int t = blockIdx.x * 256 + threadIdx.x;
    if (t >= n4) return;
    size_t e = (size_t)t * 4;
    float4 v = *(const float4*)(src + e);
    us4 hi; hi.x = f2bf(v.x); hi.y = f2bf(v.y); hi.z = f2bf(v.z); hi.w = f2bf(v.w);
    *(us4*)(dh + e) = hi;
    if (SP) {
        us4 lo;
        lo.x = f2bf(v.x - bf2f(hi.x)); lo.y = f2bf(v.y - bf2f(hi.y));
        lo.z = f2bf(v.z - bf2f(hi.z)); lo.w = f2bf(v.w - bf2f(hi.w));
        *(us4*)(dl + e) = lo;
    }
}

// ---------------------------------------------------------------- patch extract
__global__ __launch_bounds__(256) void patch_extract2_k(const float* __restrict__ img,
                                                        unsigned short* __restrict__ ph,
                                                        unsigned short* __restrict__ pl)
{
    int pi = blockIdx.x, b = blockIdx.y;
    int gy = pi / 14, gx = pi % 14;
    size_t obase = ((size_t)b * 196 + pi) * 768;
    for (int f = threadIdx.x; f < 768; f += 256) {
        int c = f >> 8, py = (f >> 4) & 15, px = f & 15;
        float v = img[(((size_t)b * 3 + c) * 224 + gy * 16 + py) * 224 + gx * 16 + px];
        unsigned short hi = f2bf(v);
        ph[obase + f] = hi;
        pl[obase + f] = f2bf(v - bf2f(hi));
    }
}

__global__ __launch_bounds__(256) void assemble_k(const float* __restrict__ emb,
                                                  const float* __restrict__ cls,
                                                  const float* __restrict__ pos,
                                                  float* __restrict__ x)
{
    int s = blockIdx.x, b = blockIdx.y;
    size_t xo = ((size_t)b * NTOK + s) * 768;
    for (int d = threadIdx.x; d < 768; d += 256) {
        float v = (s == 0) ? cls[d] : emb[((size_t)b * 196 + (s - 1)) * 768 + d];
        x[xo + d] = v + pos[(size_t)s * 768 + d];
    }
}

// ---------------------------------------------------------------- layernorm fp32 -> bf16 (OS=2: +lo plane)
template<int OS>
__global__ __launch_bounds__(256) void ln2_k(const float* __restrict__ in,
                                             unsigned short* __restrict__ outh,
                                             unsigned short* __restrict__ outl,
                                             const float* __restrict__ g,
                                             const float* __restrict__ bt, size_t ldin)
{
    const float* xr = in + (size_t)blockIdx.x * ldin;
    size_t ob = (size_t)blockIdx.x * 768;
    int t = threadIdx.x;
    float v0 = xr[t], v1 = xr[t + 256], v2 = xr[t + 512];
    float s = v0 + v1 + v2;
#pragma unroll
    for (int o = 32; o; o >>= 1) s += __shfl_xor(s, o);
    __shared__ float r1[4], r2[4];
    int wv = t >> 6, ln = t & 63;
    if (ln == 0) r1[wv] = s;
    __syncthreads();
    float mean = (r1[0] + r1[1] + r1[2] + r1[3]) * (1.f / 768.f);
    float d0 = v0 - mean, d1 = v1 - mean, d2 = v2 - mean;
    float ss = d0 * d0 + d1 * d1 + d2 * d2;
#pragma unroll
    for (int o = 32; o; o >>= 1) ss += __shfl_xor(ss, o);
    if (ln == 0) r2[wv] = ss;
    __syncthreads();
    float inv = rsqrtf((r2[0] + r2[1] + r2[2] + r2[3]) * (1.f / 768.f) + 1e-6f);
    float y0 = d0 * inv * g[t] + bt[t];
    float y1 = d1 * inv * g[t + 256] + bt[t + 256];
    float y2 = d2 * inv * g[t + 512] + bt[t + 512];
    unsigned short h0 = f2bf(y0), h1 = f2bf(y1), h2 = f2bf(y2);
    outh[ob + t] = h0; outh[ob + t + 256] = h1; outh[ob + t + 512] = h2;
    if (OS == 2) {
        outl[ob + t] = f2bf(y0 - bf2f(h0));
        outl[ob + t + 256] = f2bf(y1 - bf2f(h1));
        outl[ob + t + 512] = f2bf(y2 - bf2f(h2));
    }
}

// ---------------------------------------------------------------- 256x256 8-wave phase-pipelined GEMM
// sigma(r) = (r>>1)&3 chunk swizzle (2-way residual conflict = free).
template<int VK, int EPI, int OS>
__global__ __launch_bounds__(512, 2) void gemm256_k(const unsigned short* __restrict__ Ah,
                                                    const unsigned short* __restrict__ Al,
                                                    const unsigned short* __restrict__ Wh,
                                                    const unsigned short* __restrict__ Wl,
                                                    const float* __restrict__ bias,
                                                    const float* __restrict__ res,
                                                    unsigned short* __restrict__ Chi,
                                                    unsigned short* __restrict__ Clo,
                                                    float* __restrict__ Cf,
                                                    int M, int N, int K, int nR, int nC)
{
    extern __shared__ unsigned short lds[];   // 4 slots x (A 8192 + B 8192) shorts = 128 KiB

    const int xcd = blockIdx.x & 7, u = blockIdx.x >> 3;
    const int ct = u % nC, rl = u / nC;
    const int rt = xcd + 8 * rl;
    if (rt >= nR) return;
    const int row0 = rt << 8, col0 = ct << 8;

    const int tid = threadIdx.x;
    const int w = tid >> 6, lane = tid & 63;
    const int wr = w >> 2, wc = w & 3;            // 2 x 4 wave grid
    const int fr = lane & 15, fq = lane >> 4;
    const int aoff = (fq ^ ((fr >> 1) & 3)) << 3; // swizzled read chunk (shorts)

    const int kseg = K >> 5;
    const int nk = VK ? 3 * kseg : kseg;

    // staging: wave w covers LDS rows w*32 + (lane>>2) and +16
    const int srow = lane >> 2;
    const int r0 = (w << 5) + srow;
    const int r1 = r0 + 16;
    const int cs = (((lane & 3) ^ ((srow >> 1) & 3)) << 3);   // sigma(r0)=sigma(r1)=(srow>>1)&3
    const int gA0 = (row0 + r0 < M) ? row0 + r0 : M - 1;
    const int gA1 = (row0 + r1 < M) ? row0 + r1 : M - 1;
    const int gB0 = (col0 + r0 < N) ? col0 + r0 : N - 1;
    const int gB1 = (col0 + r1 < N) ? col0 + r1 : N - 1;

    auto stageA = [&](int kt) {
        const unsigned short* As = (!VK || kt < 2 * kseg) ? Ah : Al;
        const int k0 = (VK ? (kt >= kseg ? (kt >= 2 * kseg ? kt - 2 * kseg : kt - kseg) : kt) : kt) << 5;
        unsigned short* dst = lds + (kt & 3) * 16384 + ((w << 1) << 9);
        gload16(As + (size_t)gA0 * K + k0 + cs, dst);
        gload16(As + (size_t)gA1 * K + k0 + cs, dst + 512);
    };
    auto stageB = [&](int kt) {
        const unsigned short* Bs = (VK && kt >= kseg && kt < 2 * kseg) ? Wl : Wh;
        const int k0 = (VK ? (kt >= kseg ? (kt >= 2 * kseg ? kt - 2 * kseg : kt - kseg) : kt) : kt) << 5;
        unsigned short* dst = lds + (kt & 3) * 16384 + 8192 + ((w << 1) << 9);
        gload16(Bs + (size_t)gB0 * K + k0 + cs, dst);
        gload16(Bs + (size_t)gB1 * K + k0 + cs, dst + 512);
    };

    f32x4 acc[8][4];
#pragma unroll
    for (int m = 0; m < 8; m++)
#pragma unroll
        for (int n = 0; n < 4; n++) acc[m][n] = (f32x4)0.f;

    stageA(0); stageB(0);
    if (nk > 1) { stageA(1); stageB(1); }
    if (nk > 2) { stageA(2); stageB(2); }

#define MF4(m, av) { \
    acc[m][0] = __builtin_amdgcn_mfma_f32_16x16x32_bf16(av, b0, acc[m][0], 0, 0, 0); \
    acc[m][1] = __builtin_amdgcn_mfma_f32_16x16x32_bf16(av, b1, acc[m][1], 0, 0, 0); \
    acc[m][2] = __builtin_amdgcn_mfma_f32_16x16x32_bf16(av, b2, acc[m][2], 0, 0, 0); \
    acc[m][3] = __builtin_amdgcn_mfma_f32_16x16x32_bf16(av, b3, acc[m][3], 0, 0, 0); }

    for (int kt = 0; kt < nk; ++kt) {
        if (kt + 2 < nk)      asm volatile("s_waitcnt vmcnt(8)" ::: "memory");
        else if (kt + 1 < nk) asm volatile("s_waitcnt vmcnt(4)" ::: "memory");
        else                  asm volatile("s_waitcnt vmcnt(0)" ::: "memory");
        __builtin_amdgcn_s_barrier();
        const unsigned short* sA = lds + (kt & 3) * 16384;
        const unsigned short* sB = sA + 8192;

        short8 b0 = *(const short8*)(sB + ((wc << 6) +  0 + fr) * 32 + aoff);
        short8 b1 = *(const short8*)(sB + ((wc << 6) + 16 + fr) * 32 + aoff);
        short8 b2 = *(const short8*)(sB + ((wc << 6) + 32 + fr) * 32 + aoff);
        short8 b3 = *(const short8*)(sB + ((wc << 6) + 48 + fr) * 32 + aoff);
        short8 a0 = *(const short8*)(sA + ((wr << 7) +   0 + fr) * 32 + aoff);
        short8 a1 = *(const short8*)(sA + ((wr << 7) +  16 + fr) * 32 + aoff);
        __builtin_amdgcn_sched_barrier(0);
        if (kt + 3 < nk) stageA(kt + 3);
        __builtin_amdgcn_sched_barrier(0);
        short8 a2 = *(const short8*)(sA + ((wr << 7) +  32 + fr) * 32 + aoff);
        short8 a3 = *(const short8*)(sA + ((wr << 7) +  48 + fr) * 32 + aoff);
        __builtin_amdgcn_sched_barrier(0);
        __builtin_amdgcn_s_setprio(1);
        MF4(0, a0); MF4(1, a1);
        __builtin_amdgcn_s_setprio(0);
        __builtin_amdgcn_sched_barrier(0);
        if (kt + 3 < nk) stageB(kt + 3);
        __builtin_amdgcn_sched_barrier(0);
        short8 a4 = *(const short8*)(sA + ((wr << 7) +  64 + fr) * 32 + aoff);
        short8 a5 = *(const short8*)(sA + ((wr << 7) +  80 + fr) * 32 + aoff);
        __builtin_amdgcn_sched_barrier(0);
        __builtin_amdgcn_s_setprio(1);
        MF4(2, a2); MF4(3, a3);
        __builtin_amdgcn_s_setprio(0);
        __builtin_amdgcn_sched_barrier(0);
        short8 a6 = *(const short8*)(sA + ((wr << 7) +  96 + fr) * 32 + aoff);
        short8 a7 = *(const short8*)(sA + ((wr << 7) + 112 + fr) * 32 + aoff);
        __builtin_amdgcn_sched_barrier(0);
        __builtin_amdgcn_s_setprio(1);
        MF4(4, a4); MF4(5, a5);
        __builtin_amdgcn_s_setprio(0);
        __builtin_amdgcn_sched_barrier(0);
        __builtin_amdgcn_s_setprio(1);
        MF4(6, a6); MF4(7, a7);
        __builtin_amdgcn_s_setprio(0);
        asm volatile("s_waitcnt lgkmcnt(0)" ::: "memory");
        __builtin_amdgcn_sched_barrier(0);
    }
#undef MF4

#pragma unroll
    for (int m = 0; m < 8; m++) {
        const int rowb = row0 + (wr << 7) + (m << 4) + (fq << 2);
#pragma unroll
        for (int n = 0; n < 4; n++) {
            const int col = col0 + (wc << 6) + (n << 4) + fr;
            if (col >= N) continue;
#pragma unroll
            for (int r = 0; r < 4; r++) {
                const int row = rowb + r;
                if (row >= M) continue;
                float v = acc[m][n][r] + bias[col];
                size_t o = (size_t)row * N + col;
                if (EPI == 2) v += res[o];
                if (EPI == 1) v = 0.5f * v * (1.f + erff(v * 0.70710678118654752f));
                if (OS == 0) Cf[o] = v;
                else if (OS == 1) Chi[o] = f2bf(v);
                else { unsigned short hh = f2bf(v); Chi[o] = hh; Clo[o] = f2bf(v - bf2f(hh)); }
            }
        }
    }
}

// ---------------------------------------------------------------- 128x128 GEMM (R4)
template<int SPLIT, int EPI, int OS, int MAP>
__global__ __launch_bounds__(256) void mgemm_k(const unsigned short* __restrict__ Ah,
                                               const unsigned short* __restrict__ Al,
                                               const unsigned short* __restrict__ Wh,
                                               const unsigned short* __restrict__ Wl,
                                               const float* __restrict__ bias,
                                               const float* __restrict__ res,
                                               unsigned short* __restrict__ Chi,
                                               unsigned short* __restrict__ Clo,
                                               float* __restrict__ Cf,
                                               int M, int N, int K, int nR, int nC, int nRmax)
{
    constexpr int NP = SPLIT ? 2 : 1;
    __shared__ unsigned short lds[2 * NP * 8192];

    int rt, ct;
    {
        int bid = blockIdx.x;
        if (MAP == 0) { rt = bid % nR; ct = bid / nR; }
        else {
            int x = bid & 7, u = bid >> 3, rl, c;
            if (MAP == 2) { c = u % nC; rl = u / nC; }
            else          { rl = u % nRmax; c = u / nRmax; }
            rt = x + 8 * rl; ct = c;
            if (rt >= nR) return;
        }
    }
    const int row0 = rt << 7, col0 = ct << 7;
    const int tid = threadIdx.x;
    const int w = tid >> 6, lane = tid & 63;
    const int wr = w >> 1, wc = w & 1;
    const int srow = lane >> 2;
    const int schunk = ((lane & 3) ^ ((srow >> 1) & 3)) << 3;
    const int fr = lane & 15, fq = lane >> 4;
    const int rchunk = (fq ^ ((fr >> 1) & 3)) << 3;

    f32x4 acc[4][4];
#pragma unroll
    for (int m = 0; m < 4; m++)
#pragma unroll
        for (int n = 0; n < 4; n++) acc[m][n] = (f32x4)0.f;

    const int nk = K >> 5;

    auto stage = [&](int t, int bsel) {
        const int k0 = t << 5;
        unsigned short* Ad = lds + bsel * NP * 8192;
        unsigned short* Bd = Ad + NP * 4096;
#pragma unroll
        for (int p = 0; p < NP; p++) {
            const unsigned short* Ap = p ? Al : Ah;
            const unsigned short* Wp = p ? Wl : Wh;
#pragma unroll
            for (int i = 0; i < 2; i++) {
                int r = i * 64 + w * 16 + srow;
                int ga = row0 + r; if (ga > M - 1) ga = M - 1;
                int gb = col0 + r; if (gb > N - 1) gb = N - 1;
                gload16(Ap + (size_t)ga * K + k0 + schunk, Ad + p * 4096 + i * 2048 + w * 512);
                gload16(Wp + (size_t)gb * K + k0 + schunk, Bd + p * 4096 + i * 2048 + w * 512);
            }
        }
    };

    stage(0, 0);
    stage(1, 1);
    for (int t = 0; t < nk; ++t) {
        const int bsel = t & 1;
        if (t + 1 < nk) {
            if constexpr (NP == 2) asm volatile("s_waitcnt vmcnt(8)" ::: "memory");
            else                   asm volatile("s_waitcnt vmcnt(4)" ::: "memory");
        } else {
            asm volatile("s_waitcnt vmcnt(0)" ::: "memory");
        }
        __builtin_amdgcn_s_barrier();
        __builtin_amdgcn_sched_barrier(0);
        const unsigned short* Ab = lds + bsel * NP * 8192;
        const unsigned short* Bb = Ab + NP * 4096;
        short8 a[NP][4], bb[NP][4];
#pragma unroll
        for (int p = 0; p < NP; p++)
#pragma unroll
            for (int m = 0; m < 4; m++)
                a[p][m] = *(const short8*)(Ab + p * 4096 + (wr * 64 + m * 16 + fr) * 32 + rchunk);
#pragma unroll
        for (int p = 0; p < NP; p++)
#pragma unroll
            for (int n = 0; n < 4; n++)
                bb[p][n] = *(const short8*)(Bb + p * 4096 + (wc * 64 + n * 16 + fr) * 32 + rchunk);
        __builtin_amdgcn_sched_barrier(0);
        asm volatile("s_waitcnt lgkmcnt(0)" ::: "memory");
        __builtin_amdgcn_sched_barrier(0);
        __builtin_amdgcn_s_barrier();
        if (t + 2 < nk) stage(t + 2, bsel);
#pragma unroll
        for (int m = 0; m < 4; m++)
#pragma unroll
            for (int n = 0; n < 4; n++) {
                acc[m][n] = __builtin_amdgcn_mfma_f32_16x16x32_bf16(a[0][m], bb[0][n], acc[m][n], 0, 0, 0);
                if (SPLIT) {
                    acc[m][n] = __builtin_amdgcn_mfma_f32_16x16x32_bf16(a[0][m], bb[1][n], acc[m][n], 0, 0, 0);
                    acc[m][n] = __builtin_amdgcn_mfma_f32_16x16x32_bf16(a[1][m], bb[0][n], acc[m][n], 0, 0, 0);
                }
            }
    }

#pragma unroll
    for (int m = 0; m < 4; m++) {
#pragma unroll
        for (int n = 0; n < 4; n++) {
            int col = col0 + wc * 64 + n * 16 + fr;
#pragma unroll
            for (int r = 0; r < 4; r++) {
                int row = row0 + wr * 64 + m * 16 + fq * 4 + r;
                if (row < M && col < N) {
                    float v = acc[m][n][r] + bias[col];
                    size_t o = (size_t)row * N + col;
                    if (EPI == 2) v += res[o];
                    if (EPI == 1) v = 0.5f * v * (1.f + erff(v * 0.70710678118654752f));
                    if (OS == 0) Cf[o] = v;
                    else if (OS == 1) Chi[o] = f2bf(v);
                    else { unsigned short hh = f2bf(v); Chi[o] = hh; Clo[o] = f2bf(v - bf2f(hh)); }
                }
            }
        }
    }
}

// ---------------------------------------------------------------- fused MFMA attention
template<int SPLIT, int S, int KT, int PVKT, int PSTR>
__global__ __launch_bounds__(256) void attn2_k(const unsigned short* __restrict__ qh,
                                               const unsigned short* __restrict__ ql,
                                               unsigned short* __restrict__ oh,
                                               unsigned short* __restrict__ ol,
                                               const int* __restrict__ cntp)
{
    constexpr int NP = SPLIT ? 2 : 1;
    constexpr int PVK = PVKT * 32;
    constexpr int QT = (S + 15) / 16;
    extern __shared__ unsigned short sh[];
    unsigned short* VT = sh;
    unsigned short* PL = sh + NP * 64 * PSTR;

    const int h = blockIdx.x, b = blockIdx.y;
    const int tid = threadIdx.x, w = tid >> 6, lane = tid & 63;
    const int nk = cntp ? cntp[b] : S;
    const size_t qbase = (size_t)b * S * 2304 + (size_t)h * 64;
    const int fr = lane & 15, fq = lane >> 4;

    for (int j0 = 0; j0 < S; j0 += 32) {
        int j = j0 + (tid >> 3);
        int d8 = (tid & 7) * 8;
        if (j < S) {
            size_t src = qbase + (size_t)j * 2304 + 1536 + d8;
#pragma unroll
            for (int p = 0; p < NP; p++) {
                const unsigned short* qp = p ? ql : qh;
                short8 v = *(const short8*)(qp + src);
#pragma unroll
                for (int e = 0; e < 8; e++)
                    VT[p * 64 * PSTR + (d8 + e) * PSTR + j] = ((unsigned short*)&v)[e];
            }
        }
    }
    for (int idx = tid; idx < 64 * (PVK - S); idx += 256) {
        int d = idx / (PVK - S), j = S + idx % (PVK - S);
#pragma unroll
        for (int p = 0; p < NP; p++) VT[p * 64 * PSTR + d * PSTR + j] = 0;
    }
    {
        unsigned short* Pw = PL + w * NP * 16 * PSTR;
        for (int idx = lane; idx < 16 * (PVK - 16 * KT); idx += 64) {
            int rr = idx / (PVK - 16 * KT), cc = 16 * KT + idx % (PVK - 16 * KT);
#pragma unroll
            for (int p = 0; p < NP; p++) Pw[p * 16 * PSTR + rr * PSTR + cc] = 0;
        }
    }
    __syncthreads();

    for (int qt = w; qt < QT; qt += 4) {
        int qr = qt * 16 + fr; int qrc = qr < S ? qr : S - 1;
        const size_t qrow = qbase + (size_t)qrc * 2304;
        short8 qf0[2], qf1[2];
#pragma unroll
        for (int ks = 0; ks < 2; ks++) {
            qf0[ks] = *(const short8*)(qh + qrow + ks * 32 + fq * 8);
            if (SPLIT) qf1[ks] = *(const short8*)(ql + qrow + ks * 32 + fq * 8);
        }
        f32x4 sc[KT];
#pragma unroll
        for (int kt = 0; kt < KT; kt++) {
            int ky = kt * 16 + fr; int kyc = ky < S ? ky : S - 1;
            const size_t krow = qbase + (size_t)kyc * 2304 + 768;
            f32x4 acc = (f32x4)0.f;
#pragma unroll
            for (int ks = 0; ks < 2; ks++) {
                short8 kh = *(const short8*)(qh + krow + ks * 32 + fq * 8);
                acc = __builtin_amdgcn_mfma_f32_16x16x32_bf16(qf0[ks], kh, acc, 0, 0, 0);
                if (SPLIT) {
                    short8 kl = *(const short8*)(ql + krow + ks * 32 + fq * 8);
                    acc = __builtin_amdgcn_mfma_f32_16x16x32_bf16(qf0[ks], kl, acc, 0, 0, 0);
                    acc = __builtin_amdgcn_mfma_f32_16x16x32_bf16(qf1[ks], kh, acc, 0, 0, 0);
                }
            }
            sc[kt] = acc;
        }
        float mx[4] = {-3e38f, -3e38f, -3e38f, -3e38f};
#pragma unroll
        for (int kt = 0; kt < KT; kt++) {
            bool valid = (kt * 16 + fr) < nk;
#pragma unroll
            for (int r = 0; r < 4; r++) {
                float s = sc[kt][r] * 0.125f;
                sc[kt][r] = s;
                if (valid) mx[r] = fmaxf(mx[r], s);
            }
        }
#pragma unroll
        for (int off = 1; off < 16; off <<= 1)
#pragma unroll
            for (int r = 0; r < 4; r++) mx[r] = fmaxf(mx[r], __shfl_xor(mx[r], off));
        float sum[4] = {0.f, 0.f, 0.f, 0.f};
#pragma unroll
        for (int kt = 0; kt < KT; kt++) {
            bool valid = (kt * 16 + fr) < nk;
#pragma unroll
            for (int r = 0; r < 4; r++) {
                float p = 0.f;
                if (valid) p = SPLIT ? expf(sc[kt][r] - mx[r]) : __expf(sc[kt][r] - mx[r]);
                sc[kt][r] = p;
                sum[r] += p;
            }
        }
#pragma unroll
        for (int off = 1; off < 16; off <<= 1)
#pragma unroll
            for (int r = 0; r < 4; r++) sum[r] += __shfl_xor(sum[r], off);
        float inv[4];
#pragma unroll
        for (int r = 0; r < 4; r++) inv[r] = 1.f / sum[r];
        unsigned short* Pw = PL + w * NP * 16 * PSTR;
#pragma unroll
        for (int kt = 0; kt < KT; kt++) {
#pragma unroll
            for (int r = 0; r < 4; r++) {
                float p = sc[kt][r] * inv[r];
                unsigned short hh = f2bf(p);
                Pw[(fq * 4 + r) * PSTR + kt * 16 + fr] = hh;
                if (SPLIT) Pw[16 * PSTR + (fq * 4 + r) * PSTR + kt * 16 + fr] = f2bf(p - bf2f(hh));
            }
        }
        f32x4 o[4];
#pragma unroll
        for (int n = 0; n < 4; n++) o[n] = (f32x4)0.f;
#pragma unroll
        for (int ks = 0; ks < PVKT; ks++) {
            short8 pa = *(const short8*)(Pw + fr * PSTR + ks * 32 + fq * 8);
            short8 pl2;
            if (SPLIT) pl2 = *(const short8*)(Pw + 16 * PSTR + fr * PSTR + ks * 32 + fq * 8);
#pragma unroll
            for (int n = 0; n < 4; n++) {
                short8 vb = *(const short8*)(VT + (n * 16 + fr) * PSTR + ks * 32 + fq * 8);
                o[n] = __builtin_amdgcn_mfma_f32_16x16x32_bf16(pa, vb, o[n], 0, 0, 0);
                if (SPLIT) {
                    short8 vl = *(const short8*)(VT + 64 * PSTR + (n * 16 + fr) * PSTR + ks * 32 + fq * 8);
                    o[n] = __builtin_amdgcn_mfma_f32_16x16x32_bf16(pa, vl, o[n], 0, 0, 0);
                    o[n] = __builtin_amdgcn_mfma_f32_16x16x32_bf16(pl2, vb, o[n], 0, 0, 0);
                }
            }
        }
#pragma unroll
        for (int n = 0; n < 4; n++) {
#pragma unroll
            for (int r = 0; r < 4; r++) {
                int row = qt * 16 + fq * 4 + r;
                if (row < S) {
                    size_t oidx = ((size_t)b * S + row) * 768 + (size_t)h * 64 + n * 16 + fr;
                    float vv = o[n][r];
                    unsigned short hh = f2bf(vv);
                    oh[oidx] = hh;
                    if (SPLIT) ol[oidx] = f2bf(vv - bf2f(hh));
                }
            }
        }
    }
}

// ---------------------------------------------------------------- prune machinery
__global__ __launch_bounds__(256) void normsq_k(const float* __restrict__ x, float* __restrict__ norms)
{
    const float* xr = x + (size_t)blockIdx.x * 768;
    int t = threadIdx.x;
    float v0 = xr[t], v1 = xr[t + 256], v2 = xr[t + 512];
    float ss = v0 * v0 + v1 * v1 + v2 * v2;
#pragma unroll
    for (int o = 32; o; o >>= 1) ss += __shfl_xor(ss, o);
    __shared__ float r1[4];
    if ((t & 63) == 0) r1[t >> 6] = ss;
    __syncthreads();
    if (t == 0) norms[blockIdx.x] = r1[0] + r1[1] + r1[2] + r1[3];
}

__global__ __launch_bounds__(256) void topk_k(const float* __restrict__ norms,
                                              int* __restrict__ idxmap, int* __restrict__ cnt)
{
    int b = blockIdx.x, t = threadIdx.x;
    __shared__ float n[NTOK];
    __shared__ unsigned char kp[NTOK];
    if (t < NTOK) n[t] = norms[b * NTOK + t];
    __syncthreads();
    if (t < NTOK) {
        float me = n[t];
        int rank = 0;
        for (int j = 0; j < NTOK; j++) rank += (n[j] > me) || (n[j] == me && j < t);
        kp[t] = (rank < 98) || (t == 0);
    }
    __syncthreads();
    if (t == 0) {
        int c = 0;
        for (int s = 0; s < NTOK; s++) if (kp[s]) idxmap[b * SL + c++] = s;
        cnt[b] = c;
        for (int j = c; j < SL; j++) idxmap[b * SL + j] = 0;
    }
}

__global__ __launch_bounds__(256) void gather_k(const float* __restrict__ x, const int* __restrict__ idxmap,
                                                const int* __restrict__ cnt, float* __restrict__ xl)
{
    int j = blockIdx.x, b = blockIdx.y;
    size_t dst = ((size_t)b * SL + j) * 768;
    if (j < cnt[b]) {
        int s = idxmap[b * SL + j];
        size_t src = ((size_t)b * NTOK + s) * 768;
        for (int d = threadIdx.x; d < 768; d += 256) xl[dst + d] = x[src + d];
    } else {
        for (int d = threadIdx.x; d < 768; d += 256) xl[dst + d] = 0.f;
    }
}

// ---------------------------------------------------------------- launch
extern "C" void kernel_launch(void* const* d_in, const int* in_sizes, int n_in,
                              void* d_out, int out_size, void* d_ws, size_t ws_size,
                              hipStream_t stream)
{
    const float* images  = (const float*)d_in[0];
    const float* patch_w = (const float*)d_in[1];
    const float* patch_b = (const float*)d_in[2];
    const float* cls_tok = (const float*)d_in[3];
    const float* pos_emb = (const float*)d_in[4];
    const float* ln1_g   = (const float*)d_in[5];
    const float* ln1_b   = (const float*)d_in[6];
    const float* qkv_w   = (const float*)d_in[7];
    const float* qkv_b   = (const float*)d_in[8];
    const float* proj_w  = (const float*)d_in[9];
    const float* proj_b  = (const float*)d_in[10];
    const float* ln2_g   = (const float*)d_in[11];
    const float* ln2_b   = (const float*)d_in[12];
    const float* fc1_w   = (const float*)d_in[13];
    const float* fc1_b   = (const float*)d_in[14];
    const float* fc2_w   = (const float*)d_in[15];
    const float* fc2_b   = (const float*)d_in[16];
    const float* norm_g  = (const float*)d_in[17];
    const float* norm_b  = (const float*)d_in[18];
    const float* head_w  = (const float*)d_in[19];
    const float* head_b  = (const float*)d_in[20];
    float* outp = (float*)d_out;

    char* W = (char*)d_ws;
    float* x = (float*)W;
    unsigned short* hbh = (unsigned short*)(W + 38731776);
    unsigned short* hbl = hbh + 9682944;
    char* R = W + 77463552;
    unsigned short* wbh = (unsigned short*)(W + 232390656);
    unsigned short* wbl = wbh + 7077888;
    unsigned short* pwh = (unsigned short*)(W + 260702208);
    unsigned short* pwl = pwh + 589824;
    unsigned short* hwb = (unsigned short*)(W + 263061504);
    float* norms = (float*)(W + 264634368);
    unsigned short* clsb = (unsigned short*)(W + 264684800);
    int* idxmap = (int*)(W + 264881408);
    int* cnt    = (int*)(W + 264906752);

    unsigned short* ph  = (unsigned short*)R;
    unsigned short* plo = ph + 9633792;
    float* emb = (float*)(R + 38535168);
    unsigned short* qkh = (unsigned short*)R;
    unsigned short* qkl = qkh + 29048832;
    unsigned short* ffh = (unsigned short*)R;
    unsigned short* ffl = ffh + 38731776;
    float* xl = (float*)(R + 41943040);

    const int LDS_EARLY = (2 * 64 * 232 + 4 * 2 * 16 * 232) * 2;   // 118,784
    const int LDS_LATE  = (1 * 64 * 136 + 4 * 1 * 16 * 136) * 2;   // 34,816
    const int LDS_G256  = 131072;
    (void)hipFuncSetAttribute(reinterpret_cast<const void*>(&attn2_k<1, 197, 13, 7, 232>),
                              hipFuncAttributeMaxDynamicSharedMemorySize, LDS_EARLY);
    (void)hipFuncSetAttribute(reinterpret_cast<const void*>(&attn2_k<0, 99, 7, 4, 136>),
                              hipFuncAttributeMaxDynamicSharedMemorySize, LDS_LATE);
    (void)hipFuncSetAttribute(reinterpret_cast<const void*>(&gemm256_k<1, 0, 2>),
                              hipFuncAttributeMaxDynamicSharedMemorySize, LDS_G256);
    (void)hipFuncSetAttribute(reinterpret_cast<const void*>(&gemm256_k<1, 1, 2>),
                              hipFuncAttributeMaxDynamicSharedMemorySize, LDS_G256);

    // 256-tile grids (only where blocks >= 256): early qkv (450), early fc1 (600)
    const int nR1_256 = 50, nR1c = 7;      // M = 12608 in 256-rows
    // 128-tile grids
    const int nR1 = 99, nRm1 = 13;     // M = 12608
    const int nRp = 98, nRmp = 13;     // patch M = 12544
    const int nR2 = 50, nRm2 = 7;      // M = 6336

    // ---- patch embed (split, 128^2) ----
    cvt_simple_k<1><<<576, 256, 0, stream>>>(patch_w, pwh, pwl, 147456);
    patch_extract2_k<<<dim3(196, NB), 256, 0, stream>>>(images, ph, plo);
    mgemm_k<1, 0, 0, 2><<<8 * nRmp * 6, 256, 0, stream>>>(ph, plo, pwh, pwl, patch_b, nullptr,
        nullptr, nullptr, emb, 12544, 768, 768, nRp, 6, nRmp);
    assemble_k<<<dim3(NTOK, NB), 256, 0, stream>>>(emb, cls_tok, pos_emb, x);

    const int M1 = NB * NTOK;   // 12608
    for (int i = 0; i < 4; i++) {
        cvt_layer_k<1><<<6912, 256, 0, stream>>>(qkv_w + (size_t)i * 1769472, proj_w + (size_t)i * 589824,
                                                 fc1_w + (size_t)i * 2359296, fc2_w + (size_t)i * 2359296,
                                                 wbh, wbl);
        ln2_k<2><<<M1, 256, 0, stream>>>(x, hbh, hbl, ln1_g + (size_t)i * 768, ln1_b + (size_t)i * 768, 768);
        gemm256_k<1, 0, 2><<<8 * nR1c * 9, 512, LDS_G256, stream>>>(hbh, hbl, wbh, wbl,
            qkv_b + (size_t)i * 2304, nullptr, qkh, qkl, nullptr, M1, 2304, 768, nR1_256, 9);
        attn2_k<1, 197, 13, 7, 232><<<dim3(NHEAD, NB), 256, LDS_EARLY, stream>>>(qkh, qkl, hbh, hbl, nullptr);
        mgemm_k<1, 2, 0, 2><<<8 * nRm1 * 6, 256, 0, stream>>>(hbh, hbl, wbh + 1769472, wbl + 1769472,
            proj_b + (size_t)i * 768, x, nullptr, nullptr, x, M1, 768, 768, nR1, 6, nRm1);
        ln2_k<2><<<M1, 256, 0, stream>>>(x, hbh, hbl, ln2_g + (size_t)i * 768, ln2_b + (size_t)i * 768, 768);
        gemm256_k<1, 1, 2><<<8 * nR1c * 12, 512, LDS_G256, stream>>>(hbh, hbl, wbh + 2359296, wbl + 2359296,
            fc1_b + (size_t)i * 3072, nullptr, ffh, ffl, nullptr, M1, 3072, 768, nR1_256, 12);
        mgemm_k<1, 2, 0, 2><<<8 * nRm1 * 6, 256, 0, stream>>>(ffh, ffl, wbh + 4718592, wbl + 4718592,
            fc2_b + (size_t)i * 768, x, nullptr, nullptr, x, M1, 768, 3072, nR1, 6, nRm1);
    }

    // ---- prune + compact ----
    normsq_k<<<M1, 256, 0, stream>>>(x, norms);
    topk_k<<<NB, 256, 0, stream>>>(norms, idxmap, cnt);
    gather_k<<<dim3(SL, NB), 256, 0, stream>>>(x, idxmap, cnt, xl);

    const int M2 = NB * SL;     // 6336
    for (int i = 4; i < 12; i++) {
        cvt_layer_k<0><<<6912, 256, 0, stream>>>(qkv_w + (size_t)i * 1769472, proj_w + (size_t)i * 589824,
                                                 fc1_w + (size_t)i * 2359296, fc2_w + (size_t)i * 2359296,
                                                 wbh, nullptr);
        ln2_k<1><<<M2, 256, 0, stream>>>(xl, hbh, nullptr, ln1_g + (size_t)i * 768, ln1_b + (size_t)i * 768, 768);
        mgemm_k<0, 0, 1, 1><<<8 * nRm2 * 18, 256, 0, stream>>>(hbh, nullptr, wbh, nullptr,
            qkv_b + (size_t)i * 2304, nullptr, qkh, nullptr, nullptr, M2, 2304, 768, nR2, 18, nRm2);
        attn2_k<0, 99, 7, 4, 136><<<dim3(NHEAD, NB), 256, LDS_LATE, stream>>>(qkh, nullptr, hbl, nullptr, cnt);
        mgemm_k<0, 2, 0, 2><<<8 * nRm2 * 6, 256, 0, stream>>>(hbl, nullptr, wbh + 1769472, nullptr,
            proj_b + (size_t)i * 768, xl, nullptr, nullptr, xl, M2, 768, 768, nR2, 6, nRm2);
        ln2_k<1><<<M2, 256, 0, stream>>>(xl, hbh, nullptr, ln2_g + (size_t)i * 768, ln2_b + (size_t)i * 768, 768);
        mgemm_k<0, 1, 1, 1><<<8 * nRm2 * 24, 256, 0, stream>>>(hbh, nullptr, wbh + 2359296, nullptr,
            fc1_b + (size_t)i * 3072, nullptr, ffh, nullptr, nullptr, M2, 3072, 768, nR2, 24, nRm2);
        mgemm_k<0, 2, 0, 2><<<8 * nRm2 * 6, 256, 0, stream>>>(ffh, nullptr, wbh + 4718592, nullptr,
            fc2_b + (size_t)i * 768, xl, nullptr, nullptr, xl, M2, 768, 3072, nR2, 6, nRm2);
    }

    // ---- final LN(CLS) + head ----
    ln2_k<1><<<NB, 256, 0, stream>>>(xl, clsb, nullptr, norm_g, norm_b, (size_t)SL * 768);
    cvt_simple_k<0><<<750, 256, 0, stream>>>(head_w, hwb, nullptr, 192000);
    mgemm_k<0, 0, 0, 0><<<8, 256, 0, stream>>>(clsb, nullptr, hwb, nullptr,
        head_b, nullptr, nullptr, nullptr, outp, 64, 1000, 768, 1, 8, 1);
}

// Round 7
// 3929.849 us; speedup vs baseline: 1.7182x; 1.5279x over previous
//
#include <hip/hip_runtime.h>
#include <cstdint>
#include <cstddef>

// ViT-B/16 + token pruning. Round 7: single-plane FP16 everywhere.
// fp16 (10-bit mantissa) keeps token-norm error ~0.01% << 0.3% topk gaps,
// so the hi/lo split (3x MFMA tax) is dropped. All GEMMs use the R4 128^2
// counted-vmcnt kernel with mfma_f32_16x16x32_f16; both attention paths
// are single-plane fp16.

#define NTOK 197
#define NB 64
#define NHEAD 12
#define SL 99

typedef __attribute__((ext_vector_type(8))) _Float16 half8;
typedef __attribute__((ext_vector_type(4))) float f32x4;
typedef __attribute__((ext_vector_type(4))) unsigned short us4;

#define DEV static __device__ __forceinline__

DEV unsigned short f2h(float f) {
    union { _Float16 h; unsigned short u; } v;
    v.h = (_Float16)f;            // v_cvt_f16_f32, round-to-nearest-even
    return v.u;
}

DEV void gload16(const void* g, void* l) {
    __builtin_amdgcn_global_load_lds((const __attribute__((address_space(1))) unsigned int*)g,
                                     (__attribute__((address_space(3))) unsigned int*)l, 16, 0, 0);
}

// ---------------------------------------------------------------- weight conversion (fp32 -> fp16)
__global__ __launch_bounds__(256) void cvt_layer_k(const float* __restrict__ qw,
                                                   const float* __restrict__ pw,
                                                   const float* __restrict__ f1,
                                                   const float* __restrict__ f2,
                                                   unsigned short* __restrict__ dh)
{
    size_t t = (size_t)blockIdx.x * 256 + threadIdx.x;
    size_t e = t * 4;
    const float* src; size_t loc;
    if (e < 1769472)      { src = qw; loc = e; }
    else if (e < 2359296) { src = pw; loc = e - 1769472; }
    else if (e < 4718592) { src = f1; loc = e - 2359296; }
    else                  { src = f2; loc = e - 4718592; }
    float4 v = *(const float4*)(src + loc);
    us4 hi; hi.x = f2h(v.x); hi.y = f2h(v.y); hi.z = f2h(v.z); hi.w = f2h(v.w);
    *(us4*)(dh + e) = hi;
}

__global__ __launch_bounds__(256) void cvt_simple_k(const float* __restrict__ src,
                                                    unsigned short* __restrict__ dh, int n4)
{
    int t = blockIdx.x * 256 + threadIdx.x;
    if (t >= n4) return;
    size_t e = (size_t)t * 4;
    float4 v = *(const float4*)(src + e);
    us4 hi; hi.x = f2h(v.x); hi.y = f2h(v.y); hi.z = f2h(v.z); hi.w = f2h(v.w);
    *(us4*)(dh + e) = hi;
}

// ---------------------------------------------------------------- patch extract (fp32 -> fp16)
__global__ __launch_bounds__(256) void patch_extract2_k(const float* __restrict__ img,
                                                        unsigned short* __restrict__ ph)
{
    int pi = blockIdx.x, b = blockIdx.y;
    int gy = pi / 14, gx = pi % 14;
    size_t obase = ((size_t)b * 196 + pi) * 768;
    for (int f = threadIdx.x; f < 768; f += 256) {
        int c = f >> 8, py = (f >> 4) & 15, px = f & 15;
        float v = img[(((size_t)b * 3 + c) * 224 + gy * 16 + py) * 224 + gx * 16 + px];
        ph[obase + f] = f2h(v);
    }
}

__global__ __launch_bounds__(256) void assemble_k(const float* __restrict__ emb,
                                                  const float* __restrict__ cls,
                                                  const float* __restrict__ pos,
                                                  float* __restrict__ x)
{
    int s = blockIdx.x, b = blockIdx.y;
    size_t xo = ((size_t)b * NTOK + s) * 768;
    for (int d = threadIdx.x; d < 768; d += 256) {
        float v = (s == 0) ? cls[d] : emb[((size_t)b * 196 + (s - 1)) * 768 + d];
        x[xo + d] = v + pos[(size_t)s * 768 + d];
    }
}

// ---------------------------------------------------------------- layernorm fp32 -> fp16
__global__ __launch_bounds__(256) void ln2_k(const float* __restrict__ in,
                                             unsigned short* __restrict__ outh,
                                             const float* __restrict__ g,
                                             const float* __restrict__ bt, size_t ldin)
{
    const float* xr = in + (size_t)blockIdx.x * ldin;
    size_t ob = (size_t)blockIdx.x * 768;
    int t = threadIdx.x;
    float v0 = xr[t], v1 = xr[t + 256], v2 = xr[t + 512];
    float s = v0 + v1 + v2;
#pragma unroll
    for (int o = 32; o; o >>= 1) s += __shfl_xor(s, o);
    __shared__ float r1[4], r2[4];
    int wv = t >> 6, ln = t & 63;
    if (ln == 0) r1[wv] = s;
    __syncthreads();
    float mean = (r1[0] + r1[1] + r1[2] + r1[3]) * (1.f / 768.f);
    float d0 = v0 - mean, d1 = v1 - mean, d2 = v2 - mean;
    float ss = d0 * d0 + d1 * d1 + d2 * d2;
#pragma unroll
    for (int o = 32; o; o >>= 1) ss += __shfl_xor(ss, o);
    if (ln == 0) r2[wv] = ss;
    __syncthreads();
    float inv = rsqrtf((r2[0] + r2[1] + r2[2] + r2[3]) * (1.f / 768.f) + 1e-6f);
    outh[ob + t]       = f2h(d0 * inv * g[t]       + bt[t]);
    outh[ob + t + 256] = f2h(d1 * inv * g[t + 256] + bt[t + 256]);
    outh[ob + t + 512] = f2h(d2 * inv * g[t + 512] + bt[t + 512]);
}

// ---------------------------------------------------------------- 128x128 fp16 MFMA GEMM, counted-vmcnt
// A[M,K], W[N,K] fp16. EPI: 0 none, 1 GELU, 2 +res. OS: 0 fp32 out, 1 fp16 out.
// MAP: 0 linear, 1 xcd rows-fastest, 2 xcd cols-fastest.
template<int EPI, int OS, int MAP>
__global__ __launch_bounds__(256) void mgemm_k(const unsigned short* __restrict__ Ah,
                                               const unsigned short* __restrict__ Wh,
                                               const float* __restrict__ bias,
                                               const float* __restrict__ res,
                                               unsigned short* __restrict__ Chi,
                                               float* __restrict__ Cf,
                                               int M, int N, int K, int nR, int nC, int nRmax)
{
    __shared__ unsigned short lds[2 * 8192];

    int rt, ct;
    {
        int bid = blockIdx.x;
        if (MAP == 0) { rt = bid % nR; ct = bid / nR; }
        else {
            int x = bid & 7, u = bid >> 3, rl, c;
            if (MAP == 2) { c = u % nC; rl = u / nC; }
            else          { rl = u % nRmax; c = u / nRmax; }
            rt = x + 8 * rl; ct = c;
            if (rt >= nR) return;
        }
    }
    const int row0 = rt << 7, col0 = ct << 7;
    const int tid = threadIdx.x;
    const int w = tid >> 6, lane = tid & 63;
    const int wr = w >> 1, wc = w & 1;
    const int srow = lane >> 2;
    const int schunk = ((lane & 3) ^ ((srow >> 1) & 3)) << 3;
    const int fr = lane & 15, fq = lane >> 4;
    const int rchunk = (fq ^ ((fr >> 1) & 3)) << 3;

    f32x4 acc[4][4];
#pragma unroll
    for (int m = 0; m < 4; m++)
#pragma unroll
        for (int n = 0; n < 4; n++) acc[m][n] = (f32x4)0.f;

    const int nk = K >> 5;

    auto stage = [&](int t, int bsel) {
        const int k0 = t << 5;
        unsigned short* Ad = lds + bsel * 8192;
        unsigned short* Bd = Ad + 4096;
#pragma unroll
        for (int i = 0; i < 2; i++) {
            int r = i * 64 + w * 16 + srow;
            int ga = row0 + r; if (ga > M - 1) ga = M - 1;
            int gb = col0 + r; if (gb > N - 1) gb = N - 1;
            gload16(Ah + (size_t)ga * K + k0 + schunk, Ad + i * 2048 + w * 512);
            gload16(Wh + (size_t)gb * K + k0 + schunk, Bd + i * 2048 + w * 512);
        }
    };

    stage(0, 0);
    stage(1, 1);
    for (int t = 0; t < nk; ++t) {
        const int bsel = t & 1;
        if (t + 1 < nk) asm volatile("s_waitcnt vmcnt(4)" ::: "memory");
        else            asm volatile("s_waitcnt vmcnt(0)" ::: "memory");
        __builtin_amdgcn_s_barrier();
        __builtin_amdgcn_sched_barrier(0);
        const unsigned short* Ab = lds + bsel * 8192;
        const unsigned short* Bb = Ab + 4096;
        half8 a[4], bb[4];
#pragma unroll
        for (int m = 0; m < 4; m++)
            a[m] = *(const half8*)(Ab + (wr * 64 + m * 16 + fr) * 32 + rchunk);
#pragma unroll
        for (int n = 0; n < 4; n++)
            bb[n] = *(const half8*)(Bb + (wc * 64 + n * 16 + fr) * 32 + rchunk);
        __builtin_amdgcn_sched_barrier(0);
        asm volatile("s_waitcnt lgkmcnt(0)" ::: "memory");
        __builtin_amdgcn_sched_barrier(0);
        __builtin_amdgcn_s_barrier();
        if (t + 2 < nk) stage(t + 2, bsel);
#pragma unroll
        for (int m = 0; m < 4; m++)
#pragma unroll
            for (int n = 0; n < 4; n++)
                acc[m][n] = __builtin_amdgcn_mfma_f32_16x16x32_f16(a[m], bb[n], acc[m][n], 0, 0, 0);
    }

#pragma unroll
    for (int m = 0; m < 4; m++) {
#pragma unroll
        for (int n = 0; n < 4; n++) {
            int col = col0 + wc * 64 + n * 16 + fr;
#pragma unroll
            for (int r = 0; r < 4; r++) {
                int row = row0 + wr * 64 + m * 16 + fq * 4 + r;
                if (row < M && col < N) {
                    float v = acc[m][n][r] + bias[col];
                    size_t o = (size_t)row * N + col;
                    if (EPI == 2) v += res[o];
                    if (EPI == 1) v = 0.5f * v * (1.f + erff(v * 0.70710678118654752f));
                    if (OS == 0) Cf[o] = v;
                    else Chi[o] = f2h(v);
                }
            }
        }
    }
}

// ---------------------------------------------------------------- fused MFMA attention (fp16 single-plane)
// qkv rows [B*S, 2304]: q at h*64, k at 768+h*64, v at 1536+h*64.
template<int S, int KT, int PVKT, int PSTR>
__global__ __launch_bounds__(256) void attn2_k(const unsigned short* __restrict__ qh,
                                               unsigned short* __restrict__ oh,
                                               const int* __restrict__ cntp)
{
    constexpr int PVK = PVKT * 32;
    constexpr int QT = (S + 15) / 16;
    extern __shared__ unsigned short sh[];
    unsigned short* VT = sh;                 // [64][PSTR]  V^T
    unsigned short* PL = sh + 64 * PSTR;     // 4 waves x [16][PSTR]

    const int h = blockIdx.x, b = blockIdx.y;
    const int tid = threadIdx.x, w = tid >> 6, lane = tid & 63;
    const int nk = cntp ? cntp[b] : S;
    const size_t qbase = (size_t)b * S * 2304 + (size_t)h * 64;
    const int fr = lane & 15, fq = lane >> 4;

    for (int j0 = 0; j0 < S; j0 += 32) {
        int j = j0 + (tid >> 3);
        int d8 = (tid & 7) * 8;
        if (j < S) {
            size_t src = qbase + (size_t)j * 2304 + 1536 + d8;
            us4 v0 = *(const us4*)(qh + src);
            us4 v1 = *(const us4*)(qh + src + 4);
            VT[(d8 + 0) * PSTR + j] = v0.x; VT[(d8 + 1) * PSTR + j] = v0.y;
            VT[(d8 + 2) * PSTR + j] = v0.z; VT[(d8 + 3) * PSTR + j] = v0.w;
            VT[(d8 + 4) * PSTR + j] = v1.x; VT[(d8 + 5) * PSTR + j] = v1.y;
            VT[(d8 + 6) * PSTR + j] = v1.z; VT[(d8 + 7) * PSTR + j] = v1.w;
        }
    }
    for (int idx = tid; idx < 64 * (PVK - S); idx += 256) {
        int d = idx / (PVK - S), j = S + idx % (PVK - S);
        VT[d * PSTR + j] = 0;
    }
    {
        unsigned short* Pw = PL + w * 16 * PSTR;
        for (int idx = lane; idx < 16 * (PVK - 16 * KT); idx += 64) {
            int rr = idx / (PVK - 16 * KT), cc = 16 * KT + idx % (PVK - 16 * KT);
            Pw[rr * PSTR + cc] = 0;
        }
    }
    __syncthreads();

    for (int qt = w; qt < QT; qt += 4) {
        int qr = qt * 16 + fr; int qrc = qr < S ? qr : S - 1;
        const size_t qrow = qbase + (size_t)qrc * 2304;
        half8 qf0[2];
#pragma unroll
        for (int ks = 0; ks < 2; ks++)
            qf0[ks] = *(const half8*)(qh + qrow + ks * 32 + fq * 8);
        f32x4 sc[KT];
#pragma unroll
        for (int kt = 0; kt < KT; kt++) {
            int ky = kt * 16 + fr; int kyc = ky < S ? ky : S - 1;
            const size_t krow = qbase + (size_t)kyc * 2304 + 768;
            f32x4 acc = (f32x4)0.f;
#pragma unroll
            for (int ks = 0; ks < 2; ks++) {
                half8 kh = *(const half8*)(qh + krow + ks * 32 + fq * 8);
                acc = __builtin_amdgcn_mfma_f32_16x16x32_f16(qf0[ks], kh, acc, 0, 0, 0);
            }
            sc[kt] = acc;
        }
        float mx[4] = {-3e38f, -3e38f, -3e38f, -3e38f};
#pragma unroll
        for (int kt = 0; kt < KT; kt++) {
            bool valid = (kt * 16 + fr) < nk;
#pragma unroll
            for (int r = 0; r < 4; r++) {
                float s = sc[kt][r] * 0.125f;
                sc[kt][r] = s;
                if (valid) mx[r] = fmaxf(mx[r], s);
            }
        }
#pragma unroll
        for (int off = 1; off < 16; off <<= 1)
#pragma unroll
            for (int r = 0; r < 4; r++) mx[r] = fmaxf(mx[r], __shfl_xor(mx[r], off));
        float sum[4] = {0.f, 0.f, 0.f, 0.f};
#pragma unroll
        for (int kt = 0; kt < KT; kt++) {
            bool valid = (kt * 16 + fr) < nk;
#pragma unroll
            for (int r = 0; r < 4; r++) {
                float p = valid ? __expf(sc[kt][r] - mx[r]) : 0.f;
                sc[kt][r] = p;
                sum[r] += p;
            }
        }
#pragma unroll
        for (int off = 1; off < 16; off <<= 1)
#pragma unroll
            for (int r = 0; r < 4; r++) sum[r] += __shfl_xor(sum[r], off);
        float inv[4];
#pragma unroll
        for (int r = 0; r < 4; r++) inv[r] = 1.f / sum[r];
        unsigned short* Pw = PL + w * 16 * PSTR;
#pragma unroll
        for (int kt = 0; kt < KT; kt++) {
#pragma unroll
            for (int r = 0; r < 4; r++)
                Pw[(fq * 4 + r) * PSTR + kt * 16 + fr] = f2h(sc[kt][r] * inv[r]);
        }
        f32x4 o[4];
#pragma unroll
        for (int n = 0; n < 4; n++) o[n] = (f32x4)0.f;
#pragma unroll
        for (int ks = 0; ks < PVKT; ks++) {
            half8 pa = *(const half8*)(Pw + fr * PSTR + ks * 32 + fq * 8);
#pragma unroll
            for (int n = 0; n < 4; n++) {
                half8 vb = *(const half8*)(VT + (n * 16 + fr) * PSTR + ks * 32 + fq * 8);
                o[n] = __builtin_amdgcn_mfma_f32_16x16x32_f16(pa, vb, o[n], 0, 0, 0);
            }
        }
#pragma unroll
        for (int n = 0; n < 4; n++) {
#pragma unroll
            for (int r = 0; r < 4; r++) {
                int row = qt * 16 + fq * 4 + r;
                if (row < S) {
                    size_t oidx = ((size_t)b * S + row) * 768 + (size_t)h * 64 + n * 16 + fr;
                    oh[oidx] = f2h(o[n][r]);
                }
            }
        }
    }
}

// ---------------------------------------------------------------- prune machinery (fp32, unchanged)
__global__ __launch_bounds__(256) void normsq_k(const float* __restrict__ x, float* __restrict__ norms)
{
    const float* xr = x + (size_t)blockIdx.x * 768;
    int t = threadIdx.x;
    float v0 = xr[t], v1 = xr[t + 256], v2 = xr[t + 512];
    float ss = v0 * v0 + v1 * v1 + v2 * v2;
#pragma unroll
    for (int o = 32; o; o >>= 1) ss += __shfl_xor(ss, o);
    __shared__ float r1[4];
    if ((t & 63) == 0) r1[t >> 6] = ss;
    __syncthreads();
    if (t == 0) norms[blockIdx.x] = r1[0] + r1[1] + r1[2] + r1[3];
}

__global__ __launch_bounds__(256) void topk_k(const float* __restrict__ norms,
                                              int* __restrict__ idxmap, int* __restrict__ cnt)
{
    int b = blockIdx.x, t = threadIdx.x;
    __shared__ float n[NTOK];
    __shared__ unsigned char kp[NTOK];
    if (t < NTOK) n[t] = norms[b * NTOK + t];
    __syncthreads();
    if (t < NTOK) {
        float me = n[t];
        int rank = 0;
        for (int j = 0; j < NTOK; j++) rank += (n[j] > me) || (n[j] == me && j < t);
        kp[t] = (rank < 98) || (t == 0);
    }
    __syncthreads();
    if (t == 0) {
        int c = 0;
        for (int s = 0; s < NTOK; s++) if (kp[s]) idxmap[b * SL + c++] = s;
        cnt[b] = c;
        for (int j = c; j < SL; j++) idxmap[b * SL + j] = 0;
    }
}

__global__ __launch_bounds__(256) void gather_k(const float* __restrict__ x, const int* __restrict__ idxmap,
                                                const int* __restrict__ cnt, float* __restrict__ xl)
{
    int j = blockIdx.x, b = blockIdx.y;
    size_t dst = ((size_t)b * SL + j) * 768;
    if (j < cnt[b]) {
        int s = idxmap[b * SL + j];
        size_t src = ((size_t)b * NTOK + s) * 768;
        for (int d = threadIdx.x; d < 768; d += 256) xl[dst + d] = x[src + d];
    } else {
        for (int d = threadIdx.x; d < 768; d += 256) xl[dst + d] = 0.f;
    }
}

// ---------------------------------------------------------------- launch
extern "C" void kernel_launch(void* const* d_in, const int* in_sizes, int n_in,
                              void* d_out, int out_size, void* d_ws, size_t ws_size,
                              hipStream_t stream)
{
    const float* images  = (const float*)d_in[0];
    const float* patch_w = (const float*)d_in[1];
    const float* patch_b = (const float*)d_in[2];
    const float* cls_tok = (const float*)d_in[3];
    const float* pos_emb = (const float*)d_in[4];
    const float* ln1_g   = (const float*)d_in[5];
    const float* ln1_b   = (const float*)d_in[6];
    const float* qkv_w   = (const float*)d_in[7];
    const float* qkv_b   = (const float*)d_in[8];
    const float* proj_w  = (const float*)d_in[9];
    const float* proj_b  = (const float*)d_in[10];
    const float* ln2_g   = (const float*)d_in[11];
    const float* ln2_b   = (const float*)d_in[12];
    const float* fc1_w   = (const float*)d_in[13];
    const float* fc1_b   = (const float*)d_in[14];
    const float* fc2_w   = (const float*)d_in[15];
    const float* fc2_b   = (const float*)d_in[16];
    const float* norm_g  = (const float*)d_in[17];
    const float* norm_b  = (const float*)d_in[18];
    const float* head_w  = (const float*)d_in[19];
    const float* head_b  = (const float*)d_in[20];
    float* outp = (float*)d_out;

    char* W = (char*)d_ws;
    float* x = (float*)W;                                       // 38,731,776 B
    unsigned short* hbh = (unsigned short*)(W + 38731776);      // LN/attn-out fp16
    char* R = W + 77463552;                                     // big region
    unsigned short* wbh = (unsigned short*)(W + 232390656);     // per-layer weights fp16
    unsigned short* pwh = (unsigned short*)(W + 260702208);     // patch_w fp16
    unsigned short* hwb = (unsigned short*)(W + 263061504);     // head_w fp16
    float* norms = (float*)(W + 264634368);
    unsigned short* clsb = (unsigned short*)(W + 264684800);
    int* idxmap = (int*)(W + 264881408);
    int* cnt    = (int*)(W + 264906752);

    unsigned short* ph  = (unsigned short*)R;                   // patches fp16
    float* emb = (float*)(R + 38535168);
    unsigned short* qkh = (unsigned short*)R;                   // qkv out fp16
    unsigned short* ffh = (unsigned short*)R;                   // fc1 out fp16
    float* xl = (float*)(R + 83886080);                         // late residual fp32

    const int LDS_EARLY = (64 * 232 + 4 * 16 * 232) * 2;   // 59,392
    const int LDS_LATE  = (64 * 136 + 4 * 16 * 136) * 2;   // 34,816
    (void)hipFuncSetAttribute(reinterpret_cast<const void*>(&attn2_k<197, 13, 7, 232>),
                              hipFuncAttributeMaxDynamicSharedMemorySize, LDS_EARLY);
    (void)hipFuncSetAttribute(reinterpret_cast<const void*>(&attn2_k<99, 7, 4, 136>),
                              hipFuncAttributeMaxDynamicSharedMemorySize, LDS_LATE);

    const int nR1 = 99, nRm1 = 13;     // M = 12608
    const int nRp = 98, nRmp = 13;     // patch M = 12544
    const int nR2 = 50, nRm2 = 7;      // M = 6336

    // ---- patch embed ----
    cvt_simple_k<<<576, 256, 0, stream>>>(patch_w, pwh, 147456);
    patch_extract2_k<<<dim3(196, NB), 256, 0, stream>>>(images, ph);
    mgemm_k<0, 0, 2><<<8 * nRmp * 6, 256, 0, stream>>>(ph, pwh, patch_b, nullptr,
        nullptr, emb, 12544, 768, 768, nRp, 6, nRmp);
    assemble_k<<<dim3(NTOK, NB), 256, 0, stream>>>(emb, cls_tok, pos_emb, x);

    const int M1 = NB * NTOK;   // 12608
    for (int i = 0; i < 4; i++) {
        cvt_layer_k<<<6912, 256, 0, stream>>>(qkv_w + (size_t)i * 1769472, proj_w + (size_t)i * 589824,
                                              fc1_w + (size_t)i * 2359296, fc2_w + (size_t)i * 2359296,
                                              wbh);
        ln2_k<<<M1, 256, 0, stream>>>(x, hbh, ln1_g + (size_t)i * 768, ln1_b + (size_t)i * 768, 768);
        mgemm_k<0, 1, 1><<<8 * nRm1 * 18, 256, 0, stream>>>(hbh, wbh,
            qkv_b + (size_t)i * 2304, nullptr, qkh, nullptr, M1, 2304, 768, nR1, 18, nRm1);
        attn2_k<197, 13, 7, 232><<<dim3(NHEAD, NB), 256, LDS_EARLY, stream>>>(qkh, hbh, nullptr);
        mgemm_k<2, 0, 2><<<8 * nRm1 * 6, 256, 0, stream>>>(hbh, wbh + 1769472,
            proj_b + (size_t)i * 768, x, nullptr, x, M1, 768, 768, nR1, 6, nRm1);
        ln2_k<<<M1, 256, 0, stream>>>(x, hbh, ln2_g + (size_t)i * 768, ln2_b + (size_t)i * 768, 768);
        mgemm_k<1, 1, 1><<<8 * nRm1 * 24, 256, 0, stream>>>(hbh, wbh + 2359296,
            fc1_b + (size_t)i * 3072, nullptr, ffh, nullptr, M1, 3072, 768, nR1, 24, nRm1);
        mgemm_k<2, 0, 2><<<8 * nRm1 * 6, 256, 0, stream>>>(ffh, wbh + 4718592,
            fc2_b + (size_t)i * 768, x, nullptr, x, M1, 768, 3072, nR1, 6, nRm1);
    }

    // ---- prune + compact ----
    normsq_k<<<M1, 256, 0, stream>>>(x, norms);
    topk_k<<<NB, 256, 0, stream>>>(norms, idxmap, cnt);
    gather_k<<<dim3(SL, NB), 256, 0, stream>>>(x, idxmap, cnt, xl);

    const int M2 = NB * SL;     // 6336
    for (int i = 4; i < 12; i++) {
        cvt_layer_k<<<6912, 256, 0, stream>>>(qkv_w + (size_t)i * 1769472, proj_w + (size_t)i * 589824,
                                              fc1_w + (size_t)i * 2359296, fc2_w + (size_t)i * 2359296,
                                              wbh);
        ln2_k<<<M2, 256, 0, stream>>>(xl, hbh, ln1_g + (size_t)i * 768, ln1_b + (size_t)i * 768, 768);
        mgemm_k<0, 1, 1><<<8 * nRm2 * 18, 256, 0, stream>>>(hbh, wbh,
            qkv_b + (size_t)i * 2304, nullptr, qkh, nullptr, M2, 2304, 768, nR2, 18, nRm2);
        attn2_k<99, 7, 4, 136><<<dim3(NHEAD, NB), 256, LDS_LATE, stream>>>(qkh, hbh, cnt);
        mgemm_k<2, 0, 2><<<8 * nRm2 * 6, 256, 0, stream>>>(hbh, wbh + 1769472,
            proj_b + (size_t)i * 768, xl, nullptr, xl, M2, 768, 768, nR2, 6, nRm2);
        ln2_k<<<M2, 256, 0, stream>>>(xl, hbh, ln2_g + (size_t)i * 768, ln2_b + (size_t)i * 768, 768);
        mgemm_k<1, 1, 1><<<8 * nRm2 * 24, 256, 0, stream>>>(hbh, wbh + 2359296,
            fc1_b + (size_t)i * 3072, nullptr, ffh, nullptr, M2, 3072, 768, nR2, 24, nRm2);
        mgemm_k<2, 0, 2><<<8 * nRm2 * 6, 256, 0, stream>>>(ffh, wbh + 4718592,
            fc2_b + (size_t)i * 768, xl, nullptr, xl, M2, 768, 3072, nR2, 6, nRm2);
    }

    // ---- final LN(CLS) + head ----
    ln2_k<<<NB, 256, 0, stream>>>(xl, clsb, norm_g, norm_b, (size_t)SL * 768);
    cvt_simple_k<<<750, 256, 0, stream>>>(head_w, hwb, 192000);
    mgemm_k<0, 0, 0><<<8, 256, 0, stream>>>(clsb, hwb,
        head_b, nullptr, nullptr, outp, 64, 1000, 768, 1, 8, 1);
}